// Round 1
// baseline (1164.390 us; speedup 1.0000x reference)
//
#include <hip/hip_runtime.h>

#define NT 50000   // nodes
#define NE 800000  // edges per edge-type
#define NG 256     // graphs
#define DIM 128

// ---------------------------------------------------------------------------
// Graph ranges: goff[g] = lower_bound(graph_ids, g); graph_ids is sorted.
// ---------------------------------------------------------------------------
__global__ __launch_bounds__(256) void ranges_kernel(const int* __restrict__ gid,
                                                     int* __restrict__ goff) {
    int g = threadIdx.x;  // 0..255
    int lo = 0, hi = NT;
    while (lo < hi) {
        int mid = (lo + hi) >> 1;
        if (gid[mid] < g) lo = mid + 1; else hi = mid;
    }
    goff[g] = lo;
    if (g == 0) goff[NG] = NT;
}

// ---------------------------------------------------------------------------
// CSR build by dst: histogram -> exclusive scan -> fill
// ---------------------------------------------------------------------------
__global__ __launch_bounds__(256) void hist_kernel(const int* __restrict__ dst,
                                                   int* __restrict__ counts) {
    int i = blockIdx.x * 256 + threadIdx.x;
    if (i < NE) atomicAdd(&counts[dst[i]], 1);
}

__global__ __launch_bounds__(1024) void scan_kernel(const int* __restrict__ counts,
                                                    int* __restrict__ indptr) {
    __shared__ int part[1024];
    int tid = threadIdx.x;
    const int CH = (NT + 1023) / 1024;  // 49
    int beg = tid * CH;
    int end = beg + CH; if (end > NT) end = NT;
    int s = 0;
    for (int i = beg; i < end; ++i) s += counts[i];
    part[tid] = s;
    __syncthreads();
    for (int off = 1; off < 1024; off <<= 1) {
        int add = (tid >= off) ? part[tid - off] : 0;
        __syncthreads();
        part[tid] += add;
        __syncthreads();
    }
    int run = (tid == 0) ? 0 : part[tid - 1];
    for (int i = beg; i < end; ++i) { indptr[i] = run; run += counts[i]; }
    if (tid == 1023) indptr[NT] = run;  // == NE
}

__global__ __launch_bounds__(256) void fill_kernel(const int* __restrict__ src,
                                                   const int* __restrict__ dst,
                                                   const int* __restrict__ indptr,
                                                   int* __restrict__ cursor,
                                                   int* __restrict__ esrc) {
    int i = blockIdx.x * 256 + threadIdx.x;
    if (i < NE) {
        int d = dst[i];
        int pos = atomicAdd(&cursor[d], 1);
        esrc[indptr[d] + pos] = src[i];
    }
}

// ---------------------------------------------------------------------------
// Aggregation: x[n] = (1+eps)*h[n] + sum_{j in in(n)} h[esrc[j]]
// 32 lanes per node (float4 per lane => 512B coalesced burst per edge).
// ---------------------------------------------------------------------------
__global__ __launch_bounds__(256) void agg_kernel(const float* __restrict__ h,
                                                  const int* __restrict__ indptr,
                                                  const int* __restrict__ esrc,
                                                  const float* __restrict__ eps_p,
                                                  int eps_idx,
                                                  float* __restrict__ xout) {
    int node = blockIdx.x * 8 + (threadIdx.x >> 5);
    int c4 = threadIdx.x & 31;
    if (node >= NT) return;
    const float4* h4 = (const float4*)h;
    float e1 = 1.0f + eps_p[eps_idx];
    float4 a = h4[node * 32 + c4];
    float4 acc0 = make_float4(e1 * a.x, e1 * a.y, e1 * a.z, e1 * a.w);
    float4 acc1 = make_float4(0.f, 0.f, 0.f, 0.f);
    int beg = indptr[node], end = indptr[node + 1];
    int j = beg;
    for (; j + 2 <= end; j += 2) {
        int s0 = esrc[j], s1 = esrc[j + 1];
        float4 v0 = h4[s0 * 32 + c4];
        float4 v1 = h4[s1 * 32 + c4];
        acc0.x += v0.x; acc0.y += v0.y; acc0.z += v0.z; acc0.w += v0.w;
        acc1.x += v1.x; acc1.y += v1.y; acc1.z += v1.z; acc1.w += v1.w;
    }
    if (j < end) {
        float4 v0 = h4[esrc[j] * 32 + c4];
        acc0.x += v0.x; acc0.y += v0.y; acc0.z += v0.z; acc0.w += v0.w;
    }
    float4 r = make_float4(acc0.x + acc1.x, acc0.y + acc1.y,
                           acc0.z + acc1.z, acc0.w + acc1.w);
    ((float4*)xout)[node * 32 + c4] = r;
}

// ---------------------------------------------------------------------------
// GEMM: C[NT,128] = act( pre(A)[NT,128] @ W[128,128] + bias )
//  PRE_BN: A element -> relu(a*bn_a[k]+bn_b[k]) applied while staging to LDS
//  STATS : accumulate column sum / sumsq of C (before any relu) for BatchNorm
//  RELU  : relu on output
// Tile: 64 rows x 128 cols per block; 256 threads; thread = 8 rows x 4 cols.
// LDS: X tile 32KB + W half 32KB = 64KB -> 2 blocks/CU.
// ---------------------------------------------------------------------------
template <int PRE_BN, int STATS, int RELU>
__global__ __launch_bounds__(256) void gemm_kernel(
        const float* __restrict__ A, const float* __restrict__ W,
        const float* __restrict__ bias,
        const float* __restrict__ bn_a, const float* __restrict__ bn_b,
        float* __restrict__ C,
        float* __restrict__ gsum, float* __restrict__ gsumsq) {
    __shared__ float sX[64 * 128];  // 32 KB
    __shared__ float sW[64 * 128];  // 32 KB
    int tid = threadIdx.x;
    int tc = tid & 31;   // col group: cols 4*tc..4*tc+3
    int tr = tid >> 5;   // 0..7 : rows 8*tr..8*tr+7 (local)
    int row0 = blockIdx.x * 64;

    const float4* A4 = (const float4*)A;
    float4* sX4 = (float4*)sX;
#pragma unroll
    for (int i = 0; i < 8; ++i) {
        int idx = tid + 256 * i;       // 0..2047
        int r = idx >> 5;              // local row
        int gr = row0 + r; if (gr > NT - 1) gr = NT - 1;
        float4 v = A4[gr * 32 + (idx & 31)];
        if (PRE_BN) {
            int c = (idx & 31) * 4;
            v.x = fmaxf(0.f, fmaf(v.x, bn_a[c + 0], bn_b[c + 0]));
            v.y = fmaxf(0.f, fmaf(v.y, bn_a[c + 1], bn_b[c + 1]));
            v.z = fmaxf(0.f, fmaf(v.z, bn_a[c + 2], bn_b[c + 2]));
            v.w = fmaxf(0.f, fmaf(v.w, bn_a[c + 3], bn_b[c + 3]));
        }
        sX4[idx] = v;
    }

    float4 acc[8];
#pragma unroll
    for (int r = 0; r < 8; ++r) acc[r] = make_float4(0.f, 0.f, 0.f, 0.f);

    const float4* W4 = (const float4*)W;
    float4* sW4 = (float4*)sW;
    for (int half = 0; half < 2; ++half) {
        __syncthreads();  // X ready (first iter) / sW consumers done (second)
#pragma unroll
        for (int i = 0; i < 8; ++i) {
            int idx = tid + 256 * i;
            sW4[idx] = W4[half * 2048 + idx];
        }
        __syncthreads();
#pragma unroll 4
        for (int k0 = 0; k0 < 64; k0 += 4) {
            float4 w0 = sW4[(k0 + 0) * 32 + tc];
            float4 w1 = sW4[(k0 + 1) * 32 + tc];
            float4 w2 = sW4[(k0 + 2) * 32 + tc];
            float4 w3 = sW4[(k0 + 3) * 32 + tc];
#pragma unroll
            for (int r = 0; r < 8; ++r) {
                float4 xv = sX4[(8 * tr + r) * 32 + half * 16 + (k0 >> 2)];
                acc[r].x = fmaf(xv.x, w0.x, acc[r].x);
                acc[r].y = fmaf(xv.x, w0.y, acc[r].y);
                acc[r].z = fmaf(xv.x, w0.z, acc[r].z);
                acc[r].w = fmaf(xv.x, w0.w, acc[r].w);
                acc[r].x = fmaf(xv.y, w1.x, acc[r].x);
                acc[r].y = fmaf(xv.y, w1.y, acc[r].y);
                acc[r].z = fmaf(xv.y, w1.z, acc[r].z);
                acc[r].w = fmaf(xv.y, w1.w, acc[r].w);
                acc[r].x = fmaf(xv.z, w2.x, acc[r].x);
                acc[r].y = fmaf(xv.z, w2.y, acc[r].y);
                acc[r].z = fmaf(xv.z, w2.z, acc[r].z);
                acc[r].w = fmaf(xv.z, w2.w, acc[r].w);
                acc[r].x = fmaf(xv.w, w3.x, acc[r].x);
                acc[r].y = fmaf(xv.w, w3.y, acc[r].y);
                acc[r].z = fmaf(xv.w, w3.z, acc[r].z);
                acc[r].w = fmaf(xv.w, w3.w, acc[r].w);
            }
        }
    }

    float4 b4 = ((const float4*)bias)[tc];
#pragma unroll
    for (int r = 0; r < 8; ++r) {
        acc[r].x += b4.x; acc[r].y += b4.y; acc[r].z += b4.z; acc[r].w += b4.w;
        if (RELU) {
            acc[r].x = fmaxf(acc[r].x, 0.f); acc[r].y = fmaxf(acc[r].y, 0.f);
            acc[r].z = fmaxf(acc[r].z, 0.f); acc[r].w = fmaxf(acc[r].w, 0.f);
        }
        int gr = row0 + 8 * tr + r;
        if (gr < NT) ((float4*)C)[gr * 32 + tc] = acc[r];
    }

    if (STATS) {
        __syncthreads();
        float* ls = sX;  // reuse: [0..127]=sum, [128..255]=sumsq
        ls[tid & 255] = 0.f;
        __syncthreads();
        float s0 = 0, s1 = 0, s2 = 0, s3 = 0, q0 = 0, q1 = 0, q2 = 0, q3 = 0;
#pragma unroll
        for (int r = 0; r < 8; ++r) {
            int gr = row0 + 8 * tr + r;
            if (gr < NT) {
                s0 += acc[r].x; q0 += acc[r].x * acc[r].x;
                s1 += acc[r].y; q1 += acc[r].y * acc[r].y;
                s2 += acc[r].z; q2 += acc[r].z * acc[r].z;
                s3 += acc[r].w; q3 += acc[r].w * acc[r].w;
            }
        }
        int c0 = 4 * tc;
        atomicAdd(&ls[c0 + 0], s0); atomicAdd(&ls[c0 + 1], s1);
        atomicAdd(&ls[c0 + 2], s2); atomicAdd(&ls[c0 + 3], s3);
        atomicAdd(&ls[128 + c0 + 0], q0); atomicAdd(&ls[128 + c0 + 1], q1);
        atomicAdd(&ls[128 + c0 + 2], q2); atomicAdd(&ls[128 + c0 + 3], q3);
        __syncthreads();
        if (tid < 128) {
            atomicAdd(&gsum[tid], ls[tid]);
            atomicAdd(&gsumsq[tid], ls[128 + tid]);
        }
    }
}

// ---------------------------------------------------------------------------
// BN parameter fold: bn_a = gamma*rsqrt(var+eps), bn_b = beta - mu*bn_a
// ---------------------------------------------------------------------------
__global__ __launch_bounds__(128) void bnparam_kernel(const float* __restrict__ gsum,
                                                      const float* __restrict__ gsumsq,
                                                      const float* __restrict__ gamma,
                                                      const float* __restrict__ beta,
                                                      float* __restrict__ bn_a,
                                                      float* __restrict__ bn_b) {
    int c = threadIdx.x;
    float mu = gsum[c] * (1.0f / NT);
    float var = gsumsq[c] * (1.0f / NT) - mu * mu;
    float inv = rsqrtf(var + 1e-5f);
    float a = gamma[c] * inv;
    bn_a[c] = a;
    bn_b[c] = beta[c] - mu * a;
}

// ---------------------------------------------------------------------------
// Per-graph readout: hg[g, colOff + c] = sum over nodes of graph g of h[n, c]
// ---------------------------------------------------------------------------
__global__ __launch_bounds__(256) void readout_kernel(const float* __restrict__ h,
                                                      const int* __restrict__ goff,
                                                      float* __restrict__ hg,
                                                      int colOff) {
    int g = blockIdx.x;
    int c = threadIdx.x & 127;
    int half = threadIdx.x >> 7;
    int beg = goff[g], end = goff[g + 1];
    float acc = 0.f;
    for (int n = beg + half; n < end; n += 2) acc += h[n * 128 + c];
    __shared__ float ls[256];
    ls[threadIdx.x] = acc;
    __syncthreads();
    if (threadIdx.x < 128) hg[g * 256 + colOff + c] = ls[c] + ls[128 + c];
}

// ---------------------------------------------------------------------------
// Output MLP: out[g] = relu(relu(hg@oW1+ob1)@oW2+ob2)@oW3+ob3
// ---------------------------------------------------------------------------
__global__ __launch_bounds__(128) void mlp_kernel(const float* __restrict__ hg,
                                                  const float* __restrict__ oW1,
                                                  const float* __restrict__ ob1,
                                                  const float* __restrict__ oW2,
                                                  const float* __restrict__ ob2,
                                                  const float* __restrict__ oW3,
                                                  const float* __restrict__ ob3,
                                                  float* __restrict__ out) {
    int g = blockIdx.x, t = threadIdx.x;
    __shared__ float sh[256];
    __shared__ float z[128];
    sh[t] = hg[g * 256 + t];
    sh[t + 128] = hg[g * 256 + 128 + t];
    __syncthreads();
    float acc = ob1[t];
    for (int k = 0; k < 256; ++k) acc = fmaf(sh[k], oW1[k * 128 + t], acc);
    float z1 = fmaxf(acc, 0.f);
    z[t] = z1;
    __syncthreads();
    acc = ob2[t];
    for (int k = 0; k < 128; ++k) acc = fmaf(z[k], oW2[k * 128 + t], acc);
    float z2 = fmaxf(acc, 0.f);
    float p = z2 * oW3[t];
    for (int off = 32; off > 0; off >>= 1) p += __shfl_down(p, off, 64);
    __shared__ float wsum[2];
    if ((t & 63) == 0) wsum[t >> 6] = p;
    __syncthreads();
    if (t == 0) out[g] = wsum[0] + wsum[1] + ob3[0];
}

// ---------------------------------------------------------------------------
extern "C" void kernel_launch(void* const* d_in, const int* in_sizes, int n_in,
                              void* d_out, int out_size, void* d_ws, size_t ws_size,
                              hipStream_t stream) {
    (void)in_sizes; (void)n_in; (void)out_size; (void)ws_size;
    const float* feats = (const float*)d_in[0];
    const int*   src   = (const int*)d_in[1];     // [2, NE]
    const int*   dst   = (const int*)d_in[2];     // [2, NE]
    const int*   gid   = (const int*)d_in[3];     // [NT]
    const float* epsp  = (const float*)d_in[5];   // [2,2]
    const float* Wa    = (const float*)d_in[6];   // [2,2,128,128]
    const float* ba    = (const float*)d_in[7];   // [2,2,128]
    const float* bng   = (const float*)d_in[8];
    const float* bnb   = (const float*)d_in[9];
    const float* Wb    = (const float*)d_in[10];
    const float* bb    = (const float*)d_in[11];
    const float* oW1   = (const float*)d_in[12];
    const float* ob1   = (const float*)d_in[13];
    const float* oW2   = (const float*)d_in[14];
    const float* ob2   = (const float*)d_in[15];
    const float* oW3   = (const float*)d_in[16];
    const float* ob3   = (const float*)d_in[17];
    float* out = (float*)d_out;

    char* p = (char*)d_ws;
    auto carve = [&](size_t bytes) -> void* {
        void* r = (void*)p;
        p += (bytes + 255) & ~(size_t)255;
        return r;
    };
    float* bufP   = (float*)carve((size_t)NT * DIM * 4);
    float* bufQ   = (float*)carve((size_t)NT * DIM * 4);
    int*   esrc   = (int*)carve((size_t)NE * 4);
    int*   counts = (int*)carve((size_t)NT * 4);
    int*   indptr = (int*)carve((size_t)(NT + 1) * 4);
    int*   goff   = (int*)carve((size_t)(NG + 1) * 4);
    float* gsum   = (float*)carve(128 * 4);
    float* gsumsq = (float*)carve(128 * 4);
    float* bn_a   = (float*)carve(128 * 4);
    float* bn_b   = (float*)carve(128 * 4);
    float* hg     = (float*)carve((size_t)NG * 256 * 4);

    const int GB = (NT + 63) / 64;      // GEMM blocks
    const int EB = (NE + 255) / 256;    // edge blocks

    ranges_kernel<<<1, 256, 0, stream>>>(gid, goff);

    for (int e = 0; e < 2; ++e) {
        // CSR by dst (shared by both layers of this encoder)
        hipMemsetAsync(counts, 0, (size_t)NT * 4, stream);
        hist_kernel<<<EB, 256, 0, stream>>>(dst + e * NE, counts);
        scan_kernel<<<1, 1024, 0, stream>>>(counts, indptr);
        hipMemsetAsync(counts, 0, (size_t)NT * 4, stream);
        fill_kernel<<<EB, 256, 0, stream>>>(src + e * NE, dst + e * NE, indptr,
                                            counts, esrc);
        const float* hIn = feats;
        for (int l = 0; l < 2; ++l) {
            int wi = e * 2 + l;
            float* xb = (l == 0) ? bufQ : bufP;  // agg output / final layer output
            float* yb = (l == 0) ? bufP : bufQ;  // gemm1 output
            agg_kernel<<<(NT + 7) / 8, 256, 0, stream>>>(hIn, indptr, esrc, epsp,
                                                         wi, xb);
            hipMemsetAsync(gsum, 0, 128 * 4, stream);
            hipMemsetAsync(gsumsq, 0, 128 * 4, stream);
            gemm_kernel<0, 1, 0><<<GB, 256, 0, stream>>>(
                xb, Wa + (size_t)wi * DIM * DIM, ba + (size_t)wi * DIM,
                nullptr, nullptr, yb, gsum, gsumsq);
            bnparam_kernel<<<1, 128, 0, stream>>>(gsum, gsumsq,
                                                  bng + (size_t)wi * DIM,
                                                  bnb + (size_t)wi * DIM,
                                                  bn_a, bn_b);
            if (l == 0)
                gemm_kernel<1, 0, 1><<<GB, 256, 0, stream>>>(
                    yb, Wb + (size_t)wi * DIM * DIM, bb + (size_t)wi * DIM,
                    bn_a, bn_b, xb, nullptr, nullptr);
            else
                gemm_kernel<1, 0, 0><<<GB, 256, 0, stream>>>(
                    yb, Wb + (size_t)wi * DIM * DIM, bb + (size_t)wi * DIM,
                    bn_a, bn_b, xb, nullptr, nullptr);
            hIn = xb;
        }
        readout_kernel<<<NG, 256, 0, stream>>>(hIn, goff, hg, e * 128);
    }
    mlp_kernel<<<NG, 128, 0, stream>>>(hg, oW1, ob1, oW2, ob2, oW3, ob3, out);
}

// Round 3
// 1011.613 us; speedup vs baseline: 1.1510x; 1.1510x over previous
//
#include <hip/hip_runtime.h>

#define NT 50000   // nodes
#define NE 800000  // edges per edge-type
#define NG 256     // graphs
#define DIM 128
#define SCAN_B ((NT + 255) / 256)   // 196 scan blocks

// ---------------------------------------------------------------------------
// Graph ranges: goff[g] = lower_bound(graph_ids, g); graph_ids is sorted.
// ---------------------------------------------------------------------------
__global__ __launch_bounds__(256) void ranges_kernel(const int* __restrict__ gid,
                                                     int* __restrict__ goff) {
    int g = threadIdx.x;  // 0..255
    int lo = 0, hi = NT;
    while (lo < hi) {
        int mid = (lo + hi) >> 1;
        if (gid[mid] < g) lo = mid + 1; else hi = mid;
    }
    goff[g] = lo;
    if (g == 0) goff[NG] = NT;
}

// ---------------------------------------------------------------------------
// CSR build by dst: histogram -> 3-phase exclusive scan -> fill
// ---------------------------------------------------------------------------
__global__ __launch_bounds__(256) void hist_kernel(const int* __restrict__ dst,
                                                   int* __restrict__ counts) {
    int i = blockIdx.x * 256 + threadIdx.x;
    if (i < NE) atomicAdd(&counts[dst[i]], 1);
}

// Phase A: per-block sums of counts (196 blocks x 256)
__global__ __launch_bounds__(256) void scanA_kernel(const int* __restrict__ counts,
                                                    int* __restrict__ blockSums) {
    __shared__ int ls[256];
    int i = blockIdx.x * 256 + threadIdx.x;
    ls[threadIdx.x] = (i < NT) ? counts[i] : 0;
    __syncthreads();
#pragma unroll
    for (int off = 128; off > 0; off >>= 1) {
        if (threadIdx.x < off) ls[threadIdx.x] += ls[threadIdx.x + off];
        __syncthreads();
    }
    if (threadIdx.x == 0) blockSums[blockIdx.x] = ls[0];
}

// Phase B: exclusive scan of the 196 block sums (1 block)
__global__ __launch_bounds__(256) void scanB_kernel(const int* __restrict__ blockSums,
                                                    int* __restrict__ blockOffs) {
    __shared__ int ls[256];
    int t = threadIdx.x;
    int own = (t < SCAN_B) ? blockSums[t] : 0;
    ls[t] = own;
    __syncthreads();
#pragma unroll
    for (int off = 1; off < 256; off <<= 1) {
        int v = (t >= off) ? ls[t - off] : 0;
        __syncthreads();
        ls[t] += v;
        __syncthreads();
    }
    if (t < SCAN_B) blockOffs[t] = ls[t] - own;  // exclusive
}

// Phase C: local exclusive scan + block offset -> indptr
__global__ __launch_bounds__(256) void scanC_kernel(const int* __restrict__ counts,
                                                    const int* __restrict__ blockOffs,
                                                    int* __restrict__ indptr) {
    __shared__ int ls[256];
    int t = threadIdx.x;
    int i = blockIdx.x * 256 + t;
    int own = (i < NT) ? counts[i] : 0;
    ls[t] = own;
    __syncthreads();
#pragma unroll
    for (int off = 1; off < 256; off <<= 1) {
        int v = (t >= off) ? ls[t - off] : 0;
        __syncthreads();
        ls[t] += v;
        __syncthreads();
    }
    if (i < NT) indptr[i] = blockOffs[blockIdx.x] + ls[t] - own;
    if (i == 0) indptr[NT] = NE;  // total edge count is known
}

__global__ __launch_bounds__(256) void fill_kernel(const int* __restrict__ src,
                                                   const int* __restrict__ dst,
                                                   const int* __restrict__ indptr,
                                                   int* __restrict__ cursor,
                                                   int* __restrict__ esrc) {
    int i = blockIdx.x * 256 + threadIdx.x;
    if (i < NE) {
        int d = dst[i];
        int pos = atomicAdd(&cursor[d], 1);
        esrc[indptr[d] + pos] = src[i];
    }
}

// ---------------------------------------------------------------------------
// Aggregation: x[n] = (1+eps)*h[n] + sum_{j in in(n)} h[esrc[j]]
// 32 lanes per node (float4 per lane => 512B coalesced burst per edge).
// ---------------------------------------------------------------------------
__global__ __launch_bounds__(256) void agg_kernel(const float* __restrict__ h,
                                                  const int* __restrict__ indptr,
                                                  const int* __restrict__ esrc,
                                                  const float* __restrict__ eps_p,
                                                  int eps_idx,
                                                  float* __restrict__ xout) {
    int node = blockIdx.x * 8 + (threadIdx.x >> 5);
    int c4 = threadIdx.x & 31;
    if (node >= NT) return;
    const float4* h4 = (const float4*)h;
    float e1 = 1.0f + eps_p[eps_idx];
    float4 a = h4[node * 32 + c4];
    float4 acc0 = make_float4(e1 * a.x, e1 * a.y, e1 * a.z, e1 * a.w);
    float4 acc1 = make_float4(0.f, 0.f, 0.f, 0.f);
    int beg = indptr[node], end = indptr[node + 1];
    int j = beg;
    for (; j + 2 <= end; j += 2) {
        int s0 = esrc[j], s1 = esrc[j + 1];
        float4 v0 = h4[s0 * 32 + c4];
        float4 v1 = h4[s1 * 32 + c4];
        acc0.x += v0.x; acc0.y += v0.y; acc0.z += v0.z; acc0.w += v0.w;
        acc1.x += v1.x; acc1.y += v1.y; acc1.z += v1.z; acc1.w += v1.w;
    }
    if (j < end) {
        float4 v0 = h4[esrc[j] * 32 + c4];
        acc0.x += v0.x; acc0.y += v0.y; acc0.z += v0.z; acc0.w += v0.w;
    }
    float4 r = make_float4(acc0.x + acc1.x, acc0.y + acc1.y,
                           acc0.z + acc1.z, acc0.w + acc1.w);
    ((float4*)xout)[node * 32 + c4] = r;
}

// ---------------------------------------------------------------------------
// GEMM: C[NT,128] = act( pre(A)[NT,128] @ W[128,128] + bias )
//  PRE_BN: A element -> relu(a*bn_a[k]+bn_b[k]) applied while staging to LDS
//  STATS : accumulate column sum / sumsq of C (before any relu) for BatchNorm
//  RELU  : relu on output
// Tile: 64 rows x 128 cols per block; 256 threads; thread = 8 rows x 4 cols.
// LDS: X tile 32KB + W half 32KB = 64KB -> 2 blocks/CU.
// ---------------------------------------------------------------------------
template <int PRE_BN, int STATS, int RELU>
__global__ __launch_bounds__(256) void gemm_kernel(
        const float* __restrict__ A, const float* __restrict__ W,
        const float* __restrict__ bias,
        const float* __restrict__ bn_a, const float* __restrict__ bn_b,
        float* __restrict__ C,
        float* __restrict__ gsum, float* __restrict__ gsumsq) {
    __shared__ float sX[64 * 128];  // 32 KB
    __shared__ float sW[64 * 128];  // 32 KB
    int tid = threadIdx.x;
    int tc = tid & 31;   // col group: cols 4*tc..4*tc+3
    int tr = tid >> 5;   // 0..7 : rows 8*tr..8*tr+7 (local)
    int row0 = blockIdx.x * 64;

    const float4* A4 = (const float4*)A;
    float4* sX4 = (float4*)sX;
#pragma unroll
    for (int i = 0; i < 8; ++i) {
        int idx = tid + 256 * i;       // 0..2047
        int r = idx >> 5;              // local row
        int gr = row0 + r; if (gr > NT - 1) gr = NT - 1;
        float4 v = A4[gr * 32 + (idx & 31)];
        if (PRE_BN) {
            int c = (idx & 31) * 4;
            v.x = fmaxf(0.f, fmaf(v.x, bn_a[c + 0], bn_b[c + 0]));
            v.y = fmaxf(0.f, fmaf(v.y, bn_a[c + 1], bn_b[c + 1]));
            v.z = fmaxf(0.f, fmaf(v.z, bn_a[c + 2], bn_b[c + 2]));
            v.w = fmaxf(0.f, fmaf(v.w, bn_a[c + 3], bn_b[c + 3]));
        }
        sX4[idx] = v;
    }

    float4 acc[8];
#pragma unroll
    for (int r = 0; r < 8; ++r) acc[r] = make_float4(0.f, 0.f, 0.f, 0.f);

    const float4* W4 = (const float4*)W;
    float4* sW4 = (float4*)sW;
    for (int half = 0; half < 2; ++half) {
        __syncthreads();  // X ready (first iter) / sW consumers done (second)
#pragma unroll
        for (int i = 0; i < 8; ++i) {
            int idx = tid + 256 * i;
            sW4[idx] = W4[half * 2048 + idx];
        }
        __syncthreads();
#pragma unroll 4
        for (int k0 = 0; k0 < 64; k0 += 4) {
            float4 w0 = sW4[(k0 + 0) * 32 + tc];
            float4 w1 = sW4[(k0 + 1) * 32 + tc];
            float4 w2 = sW4[(k0 + 2) * 32 + tc];
            float4 w3 = sW4[(k0 + 3) * 32 + tc];
#pragma unroll
            for (int r = 0; r < 8; ++r) {
                float4 xv = sX4[(8 * tr + r) * 32 + half * 16 + (k0 >> 2)];
                acc[r].x = fmaf(xv.x, w0.x, acc[r].x);
                acc[r].y = fmaf(xv.x, w0.y, acc[r].y);
                acc[r].z = fmaf(xv.x, w0.z, acc[r].z);
                acc[r].w = fmaf(xv.x, w0.w, acc[r].w);
                acc[r].x = fmaf(xv.y, w1.x, acc[r].x);
                acc[r].y = fmaf(xv.y, w1.y, acc[r].y);
                acc[r].z = fmaf(xv.y, w1.z, acc[r].z);
                acc[r].w = fmaf(xv.y, w1.w, acc[r].w);
                acc[r].x = fmaf(xv.z, w2.x, acc[r].x);
                acc[r].y = fmaf(xv.z, w2.y, acc[r].y);
                acc[r].z = fmaf(xv.z, w2.z, acc[r].z);
                acc[r].w = fmaf(xv.z, w2.w, acc[r].w);
                acc[r].x = fmaf(xv.w, w3.x, acc[r].x);
                acc[r].y = fmaf(xv.w, w3.y, acc[r].y);
                acc[r].z = fmaf(xv.w, w3.z, acc[r].z);
                acc[r].w = fmaf(xv.w, w3.w, acc[r].w);
            }
        }
    }

    float4 b4 = ((const float4*)bias)[tc];
#pragma unroll
    for (int r = 0; r < 8; ++r) {
        acc[r].x += b4.x; acc[r].y += b4.y; acc[r].z += b4.z; acc[r].w += b4.w;
        if (RELU) {
            acc[r].x = fmaxf(acc[r].x, 0.f); acc[r].y = fmaxf(acc[r].y, 0.f);
            acc[r].z = fmaxf(acc[r].z, 0.f); acc[r].w = fmaxf(acc[r].w, 0.f);
        }
        int gr = row0 + 8 * tr + r;
        if (gr < NT) ((float4*)C)[gr * 32 + tc] = acc[r];
    }

    if (STATS) {
        __syncthreads();
        float* ls = sX;  // reuse: [0..127]=sum, [128..255]=sumsq
        ls[tid & 255] = 0.f;
        __syncthreads();
        float s0 = 0, s1 = 0, s2 = 0, s3 = 0, q0 = 0, q1 = 0, q2 = 0, q3 = 0;
#pragma unroll
        for (int r = 0; r < 8; ++r) {
            int gr = row0 + 8 * tr + r;
            if (gr < NT) {
                s0 += acc[r].x; q0 += acc[r].x * acc[r].x;
                s1 += acc[r].y; q1 += acc[r].y * acc[r].y;
                s2 += acc[r].z; q2 += acc[r].z * acc[r].z;
                s3 += acc[r].w; q3 += acc[r].w * acc[r].w;
            }
        }
        int c0 = 4 * tc;
        atomicAdd(&ls[c0 + 0], s0); atomicAdd(&ls[c0 + 1], s1);
        atomicAdd(&ls[c0 + 2], s2); atomicAdd(&ls[c0 + 3], s3);
        atomicAdd(&ls[128 + c0 + 0], q0); atomicAdd(&ls[128 + c0 + 1], q1);
        atomicAdd(&ls[128 + c0 + 2], q2); atomicAdd(&ls[128 + c0 + 3], q3);
        __syncthreads();
        if (tid < 128) {
            atomicAdd(&gsum[tid], ls[tid]);
            atomicAdd(&gsumsq[tid], ls[128 + tid]);
        }
    }
}

// ---------------------------------------------------------------------------
// BN parameter fold: bn_a = gamma*rsqrt(var+eps), bn_b = beta - mu*bn_a
// ---------------------------------------------------------------------------
__global__ __launch_bounds__(128) void bnparam_kernel(const float* __restrict__ gsum,
                                                      const float* __restrict__ gsumsq,
                                                      const float* __restrict__ gamma,
                                                      const float* __restrict__ beta,
                                                      float* __restrict__ bn_a,
                                                      float* __restrict__ bn_b) {
    int c = threadIdx.x;
    float mu = gsum[c] * (1.0f / NT);
    float var = gsumsq[c] * (1.0f / NT) - mu * mu;
    float inv = rsqrtf(var + 1e-5f);
    float a = gamma[c] * inv;
    bn_a[c] = a;
    bn_b[c] = beta[c] - mu * a;
}

// ---------------------------------------------------------------------------
// Per-graph readout: hg[g, colOff + c] = sum over nodes of graph g of h[n, c]
// ---------------------------------------------------------------------------
__global__ __launch_bounds__(256) void readout_kernel(const float* __restrict__ h,
                                                      const int* __restrict__ goff,
                                                      float* __restrict__ hg,
                                                      int colOff) {
    int g = blockIdx.x;
    int c = threadIdx.x & 127;
    int half = threadIdx.x >> 7;
    int beg = goff[g], end = goff[g + 1];
    float acc = 0.f;
    for (int n = beg + half; n < end; n += 2) acc += h[n * 128 + c];
    __shared__ float ls[256];
    ls[threadIdx.x] = acc;
    __syncthreads();
    if (threadIdx.x < 128) hg[g * 256 + colOff + c] = ls[c] + ls[128 + c];
}

// ---------------------------------------------------------------------------
// Output MLP: out[g] = relu(relu(hg@oW1+ob1)@oW2+ob2)@oW3+ob3
// ---------------------------------------------------------------------------
__global__ __launch_bounds__(128) void mlp_kernel(const float* __restrict__ hg,
                                                  const float* __restrict__ oW1,
                                                  const float* __restrict__ ob1,
                                                  const float* __restrict__ oW2,
                                                  const float* __restrict__ ob2,
                                                  const float* __restrict__ oW3,
                                                  const float* __restrict__ ob3,
                                                  float* __restrict__ out) {
    int g = blockIdx.x, t = threadIdx.x;
    __shared__ float sh[256];
    __shared__ float z[128];
    sh[t] = hg[g * 256 + t];
    sh[t + 128] = hg[g * 256 + 128 + t];
    __syncthreads();
    float acc = ob1[t];
    for (int k = 0; k < 256; ++k) acc = fmaf(sh[k], oW1[k * 128 + t], acc);
    float z1 = fmaxf(acc, 0.f);
    z[t] = z1;
    __syncthreads();
    acc = ob2[t];
    for (int k = 0; k < 128; ++k) acc = fmaf(z[k], oW2[k * 128 + t], acc);
    float z2 = fmaxf(acc, 0.f);
    float p = z2 * oW3[t];
    for (int off = 32; off > 0; off >>= 1) p += __shfl_down(p, off, 64);
    __shared__ float wsum[2];
    if ((t & 63) == 0) wsum[t >> 6] = p;
    __syncthreads();
    if (t == 0) out[g] = wsum[0] + wsum[1] + ob3[0];
}

// ---------------------------------------------------------------------------
extern "C" void kernel_launch(void* const* d_in, const int* in_sizes, int n_in,
                              void* d_out, int out_size, void* d_ws, size_t ws_size,
                              hipStream_t stream) {
    (void)in_sizes; (void)n_in; (void)out_size; (void)ws_size;
    const float* feats = (const float*)d_in[0];
    const int*   src   = (const int*)d_in[1];     // [2, NE]
    const int*   dst   = (const int*)d_in[2];     // [2, NE]
    const int*   gid   = (const int*)d_in[3];     // [NT]
    const float* epsp  = (const float*)d_in[5];   // [2,2]
    const float* Wa    = (const float*)d_in[6];   // [2,2,128,128]
    const float* ba    = (const float*)d_in[7];   // [2,2,128]
    const float* bng   = (const float*)d_in[8];
    const float* bnb   = (const float*)d_in[9];
    const float* Wb    = (const float*)d_in[10];
    const float* bb    = (const float*)d_in[11];
    const float* oW1   = (const float*)d_in[12];
    const float* ob1   = (const float*)d_in[13];
    const float* oW2   = (const float*)d_in[14];
    const float* ob2   = (const float*)d_in[15];
    const float* oW3   = (const float*)d_in[16];
    const float* ob3   = (const float*)d_in[17];
    float* out = (float*)d_out;

    char* p = (char*)d_ws;
    auto carve = [&](size_t bytes) -> void* {
        void* r = (void*)p;
        p += (bytes + 255) & ~(size_t)255;
        return r;
    };
    float* bufP    = (float*)carve((size_t)NT * DIM * 4);
    float* bufQ    = (float*)carve((size_t)NT * DIM * 4);
    int*   esrc    = (int*)carve((size_t)NE * 4);
    // counts and cursor MUST be one contiguous carve: they are zeroed by a
    // single fused memset. (R2 bug: separate carves got 256B alignment pad,
    // leaving the tail of cursor poisoned -> OOB writes in fill_kernel.)
    int*   counts  = (int*)carve((size_t)NT * 2 * 4);
    int*   cursor  = counts + NT;
    int*   indptr  = (int*)carve((size_t)(NT + 1) * 4);
    int*   bsums   = (int*)carve((size_t)SCAN_B * 4);
    int*   boffs   = (int*)carve((size_t)SCAN_B * 4);
    int*   goff    = (int*)carve((size_t)(NG + 1) * 4);
    float* gsum    = (float*)carve(2 * 128 * 4);  // gsum+gsumsq contiguous
    float* gsumsq  = gsum + 128;
    float* bn_a    = (float*)carve(128 * 4);
    float* bn_b    = (float*)carve(128 * 4);
    float* hg      = (float*)carve((size_t)NG * 256 * 4);

    const int GB = (NT + 63) / 64;      // GEMM blocks
    const int EB = (NE + 255) / 256;    // edge blocks

    ranges_kernel<<<1, 256, 0, stream>>>(gid, goff);

    for (int e = 0; e < 2; ++e) {
        // CSR by dst (shared by both layers of this encoder)
        hipMemsetAsync(counts, 0, (size_t)NT * 2 * 4, stream);  // counts + cursor
        hist_kernel<<<EB, 256, 0, stream>>>(dst + e * NE, counts);
        scanA_kernel<<<SCAN_B, 256, 0, stream>>>(counts, bsums);
        scanB_kernel<<<1, 256, 0, stream>>>(bsums, boffs);
        scanC_kernel<<<SCAN_B, 256, 0, stream>>>(counts, boffs, indptr);
        fill_kernel<<<EB, 256, 0, stream>>>(src + e * NE, dst + e * NE, indptr,
                                            cursor, esrc);
        const float* hIn = feats;
        for (int l = 0; l < 2; ++l) {
            int wi = e * 2 + l;
            float* xb = (l == 0) ? bufQ : bufP;  // agg output / final layer output
            float* yb = (l == 0) ? bufP : bufQ;  // gemm1 output
            agg_kernel<<<(NT + 7) / 8, 256, 0, stream>>>(hIn, indptr, esrc, epsp,
                                                         wi, xb);
            hipMemsetAsync(gsum, 0, 2 * 128 * 4, stream);  // gsum + gsumsq
            gemm_kernel<0, 1, 0><<<GB, 256, 0, stream>>>(
                xb, Wa + (size_t)wi * DIM * DIM, ba + (size_t)wi * DIM,
                nullptr, nullptr, yb, gsum, gsumsq);
            bnparam_kernel<<<1, 128, 0, stream>>>(gsum, gsumsq,
                                                  bng + (size_t)wi * DIM,
                                                  bnb + (size_t)wi * DIM,
                                                  bn_a, bn_b);
            if (l == 0)
                gemm_kernel<1, 0, 1><<<GB, 256, 0, stream>>>(
                    yb, Wb + (size_t)wi * DIM * DIM, bb + (size_t)wi * DIM,
                    bn_a, bn_b, xb, nullptr, nullptr);
            else
                gemm_kernel<1, 0, 0><<<GB, 256, 0, stream>>>(
                    yb, Wb + (size_t)wi * DIM * DIM, bb + (size_t)wi * DIM,
                    bn_a, bn_b, xb, nullptr, nullptr);
            hIn = xb;
        }
        readout_kernel<<<NG, 256, 0, stream>>>(hIn, goff, hg, e * 128);
    }
    mlp_kernel<<<NG, 128, 0, stream>>>(hg, oW1, ob1, oW2, ob2, oW3, ob3, out);
}

// Round 4
// 780.652 us; speedup vs baseline: 1.4916x; 1.2959x over previous
//
#include <hip/hip_runtime.h>

#define NT 50000   // nodes
#define NE 800000  // edges per edge-type
#define NG 256     // graphs
#define DIM 128
#define SCAN_B ((NT + 255) / 256)    // 196 scan blocks
#define GEMM_B ((NT + 127) / 128)    // 391 MFMA-GEMM blocks

typedef short s16x8 __attribute__((ext_vector_type(8)));
typedef float f32x16 __attribute__((ext_vector_type(16)));

__device__ __forceinline__ unsigned short f32_to_bf16(float f) {
    unsigned int u = __float_as_uint(f);
    u += 0x7FFFu + ((u >> 16) & 1u);   // round-to-nearest-even
    return (unsigned short)(u >> 16);
}
__device__ __forceinline__ float bf16_to_f32(unsigned short h) {
    return __uint_as_float(((unsigned int)h) << 16);
}

// ---------------------------------------------------------------------------
// Graph ranges: goff[g] = lower_bound(graph_ids, g); graph_ids is sorted.
// ---------------------------------------------------------------------------
__global__ __launch_bounds__(256) void ranges_kernel(const int* __restrict__ gid,
                                                     int* __restrict__ goff) {
    int g = threadIdx.x;
    int lo = 0, hi = NT;
    while (lo < hi) {
        int mid = (lo + hi) >> 1;
        if (gid[mid] < g) lo = mid + 1; else hi = mid;
    }
    goff[g] = lo;
    if (g == 0) goff[NG] = NT;
}

// ---------------------------------------------------------------------------
// CSR build by dst: histogram -> 3-phase exclusive scan -> fill
// ---------------------------------------------------------------------------
__global__ __launch_bounds__(256) void hist_kernel(const int* __restrict__ dst,
                                                   int* __restrict__ counts) {
    int i = blockIdx.x * 256 + threadIdx.x;
    if (i < NE) atomicAdd(&counts[dst[i]], 1);
}

__global__ __launch_bounds__(256) void scanA_kernel(const int* __restrict__ counts,
                                                    int* __restrict__ blockSums) {
    __shared__ int ls[256];
    int i = blockIdx.x * 256 + threadIdx.x;
    ls[threadIdx.x] = (i < NT) ? counts[i] : 0;
    __syncthreads();
#pragma unroll
    for (int off = 128; off > 0; off >>= 1) {
        if (threadIdx.x < off) ls[threadIdx.x] += ls[threadIdx.x + off];
        __syncthreads();
    }
    if (threadIdx.x == 0) blockSums[blockIdx.x] = ls[0];
}

__global__ __launch_bounds__(256) void scanB_kernel(const int* __restrict__ blockSums,
                                                    int* __restrict__ blockOffs) {
    __shared__ int ls[256];
    int t = threadIdx.x;
    int own = (t < SCAN_B) ? blockSums[t] : 0;
    ls[t] = own;
    __syncthreads();
#pragma unroll
    for (int off = 1; off < 256; off <<= 1) {
        int v = (t >= off) ? ls[t - off] : 0;
        __syncthreads();
        ls[t] += v;
        __syncthreads();
    }
    if (t < SCAN_B) blockOffs[t] = ls[t] - own;
}

__global__ __launch_bounds__(256) void scanC_kernel(const int* __restrict__ counts,
                                                    const int* __restrict__ blockOffs,
                                                    int* __restrict__ indptr) {
    __shared__ int ls[256];
    int t = threadIdx.x;
    int i = blockIdx.x * 256 + t;
    int own = (i < NT) ? counts[i] : 0;
    ls[t] = own;
    __syncthreads();
#pragma unroll
    for (int off = 1; off < 256; off <<= 1) {
        int v = (t >= off) ? ls[t - off] : 0;
        __syncthreads();
        ls[t] += v;
        __syncthreads();
    }
    if (i < NT) indptr[i] = blockOffs[blockIdx.x] + ls[t] - own;
    if (i == 0) indptr[NT] = NE;
}

__global__ __launch_bounds__(256) void fill_kernel(const int* __restrict__ src,
                                                   const int* __restrict__ dst,
                                                   const int* __restrict__ indptr,
                                                   int* __restrict__ cursor,
                                                   int* __restrict__ esrc) {
    int i = blockIdx.x * 256 + threadIdx.x;
    if (i < NE) {
        int d = dst[i];
        int pos = atomicAdd(&cursor[d], 1);
        esrc[indptr[d] + pos] = src[i];
    }
}

// ---------------------------------------------------------------------------
// Aggregation + bf16 hi/lo split: x[n] = (1+eps)*h[n] + sum h[esrc[j]]
// Output layout per row: [hi(128 bf16) | lo(128 bf16)]  (512 B/row)
// ---------------------------------------------------------------------------
__global__ __launch_bounds__(256) void agg_split_kernel(const float* __restrict__ h,
        const int* __restrict__ indptr, const int* __restrict__ esrc,
        const float* __restrict__ eps_p, int eps_idx,
        unsigned short* __restrict__ xout) {
    int node = blockIdx.x * 8 + (threadIdx.x >> 5);
    int c4 = threadIdx.x & 31;
    if (node >= NT) return;
    const float4* h4 = (const float4*)h;
    float e1 = 1.0f + eps_p[eps_idx];
    float4 a = h4[(size_t)node * 32 + c4];
    float4 acc0 = make_float4(e1 * a.x, e1 * a.y, e1 * a.z, e1 * a.w);
    float4 acc1 = make_float4(0.f, 0.f, 0.f, 0.f);
    int beg = indptr[node], end = indptr[node + 1];
    int j = beg;
    for (; j + 2 <= end; j += 2) {
        int s0 = esrc[j], s1 = esrc[j + 1];
        float4 v0 = h4[(size_t)s0 * 32 + c4];
        float4 v1 = h4[(size_t)s1 * 32 + c4];
        acc0.x += v0.x; acc0.y += v0.y; acc0.z += v0.z; acc0.w += v0.w;
        acc1.x += v1.x; acc1.y += v1.y; acc1.z += v1.z; acc1.w += v1.w;
    }
    if (j < end) {
        float4 v0 = h4[(size_t)esrc[j] * 32 + c4];
        acc0.x += v0.x; acc0.y += v0.y; acc0.z += v0.z; acc0.w += v0.w;
    }
    float4 r = make_float4(acc0.x + acc1.x, acc0.y + acc1.y,
                           acc0.z + acc1.z, acc0.w + acc1.w);
    ushort4 hv, lv;
    hv.x = f32_to_bf16(r.x); lv.x = f32_to_bf16(r.x - bf16_to_f32(hv.x));
    hv.y = f32_to_bf16(r.y); lv.y = f32_to_bf16(r.y - bf16_to_f32(hv.y));
    hv.z = f32_to_bf16(r.z); lv.z = f32_to_bf16(r.z - bf16_to_f32(hv.z));
    hv.w = f32_to_bf16(r.w); lv.w = f32_to_bf16(r.w - bf16_to_f32(hv.w));
    *(ushort4*)(xout + (size_t)node * 256 + c4 * 4) = hv;
    *(ushort4*)(xout + (size_t)node * 256 + 128 + c4 * 4) = lv;
}

// ---------------------------------------------------------------------------
// Weight split + frag-major repack. For each 128x128 W: rows 0..127 of B' =
// bf16(W) (hi), rows 128..255 = bf16(W - hi) (lo). Stored in the exact order
// the GEMM's wave lanes consume: unit u = (nt*16+kcp)*64 + kg*32 + nin,
// element j; lane l=kg*32+nin reads unit (nt*16+kcp)*64+l as one ds_read_b128.
// ---------------------------------------------------------------------------
__global__ __launch_bounds__(256) void bsplit_kernel(const float* __restrict__ Wa,
                                                     const float* __restrict__ Wb,
                                                     unsigned short* __restrict__ Bfrag) {
    int slot = blockIdx.x >> 3;   // 0..7 : 0..3=Wa[e,l], 4..7=Wb[e,l]
    int sub = blockIdx.x & 7;
    const float* W = (slot < 4) ? (Wa + (size_t)slot * DIM * DIM)
                                : (Wb + (size_t)(slot - 4) * DIM * DIM);
    unsigned short* out = Bfrag + (size_t)slot * 32768;
    for (int i = 0; i < 16; ++i) {
        int e = sub * 4096 + i * 256 + threadIdx.x;  // 0..32767
        int kphys = e >> 7, n = e & 127;
        int k = kphys & 127;
        float wv = W[k * 128 + n];
        unsigned short hi = f32_to_bf16(wv);
        unsigned short val = (kphys < 128) ? hi : f32_to_bf16(wv - bf16_to_f32(hi));
        int nt = n >> 5, nin = n & 31;
        int kcp = kphys >> 4, kgp = (kphys >> 3) & 1, jj = kphys & 7;
        out[(size_t)(((nt * 16 + kcp) * 64) + kgp * 32 + nin) * 8 + jj] = val;
    }
}

// ---------------------------------------------------------------------------
// MFMA GEMM: C[NT,128] = act( pre(A)[NT,128] @ W[128,128] + bias )
// 3-term bf16 split: Ahi*Bhi + Alo*Bhi + Ahi*Blo (fp32 MFMA accumulate).
// Block: 256 thr = 4 waves; tile 128 rows x 128 cols; wave = 32 rows.
// A frags in registers (16x ds-free global 16B loads); whole B' (64KB) in LDS.
// SRC_FP32: A read as fp32 + fused BN+ReLU + split (gemm2 path).
// STATS: per-column sum/sumsq of (A@W+bias) for BatchNorm (gemm1 path).
// ---------------------------------------------------------------------------
template <int SRC_FP32, int STATS, int RELU>
__global__ __launch_bounds__(256) void mfma_gemm_kernel(
        const void* __restrict__ Asrc,
        const unsigned short* __restrict__ Bfrag,
        const float* __restrict__ bias,
        const float* __restrict__ bn_a, const float* __restrict__ bn_b,
        float* __restrict__ C,
        float* __restrict__ gsum, float* __restrict__ gsumsq) {
    __shared__ char smem[65536];
    unsigned short* sB = (unsigned short*)smem;
    const int tid = threadIdx.x;
    const int w = tid >> 6, lane = tid & 63;
    const int nin = lane & 31, kg = lane >> 5;
    const int row0 = blockIdx.x * 128;
    const int myrow = row0 + w * 32 + nin;
    const int rowc = myrow < NT ? myrow : NT - 1;

    // stage whole B' into LDS (straight coalesced copy, frag-major layout)
    {
        const uint4* Bg = (const uint4*)Bfrag;
        uint4* sB4 = (uint4*)smem;
#pragma unroll
        for (int i = 0; i < 16; ++i) sB4[tid + 256 * i] = Bg[tid + 256 * i];
    }

    // A fragments: lane holds rows rowc, k = kc*16 + kg*8 + j
    s16x8 ahi[8], alo[8];
    if (!SRC_FP32) {
        const unsigned short* ar = (const unsigned short*)Asrc + (size_t)rowc * 256 + kg * 8;
#pragma unroll
        for (int kc = 0; kc < 8; ++kc) {
            ahi[kc] = *(const s16x8*)(ar + kc * 16);
            alo[kc] = *(const s16x8*)(ar + 128 + kc * 16);
        }
    } else {
        const float* yr = (const float*)Asrc + (size_t)rowc * 128 + kg * 8;
#pragma unroll
        for (int kc = 0; kc < 8; ++kc) {
            int c0 = kc * 16 + kg * 8;
            float4 y0 = *(const float4*)(yr + kc * 16);
            float4 y1 = *(const float4*)(yr + kc * 16 + 4);
            float4 a0 = *(const float4*)(bn_a + c0);
            float4 a1 = *(const float4*)(bn_a + c0 + 4);
            float4 b0 = *(const float4*)(bn_b + c0);
            float4 b1 = *(const float4*)(bn_b + c0 + 4);
            float t[8];
            t[0] = fmaxf(0.f, fmaf(y0.x, a0.x, b0.x));
            t[1] = fmaxf(0.f, fmaf(y0.y, a0.y, b0.y));
            t[2] = fmaxf(0.f, fmaf(y0.z, a0.z, b0.z));
            t[3] = fmaxf(0.f, fmaf(y0.w, a0.w, b0.w));
            t[4] = fmaxf(0.f, fmaf(y1.x, a1.x, b1.x));
            t[5] = fmaxf(0.f, fmaf(y1.y, a1.y, b1.y));
            t[6] = fmaxf(0.f, fmaf(y1.z, a1.z, b1.z));
            t[7] = fmaxf(0.f, fmaf(y1.w, a1.w, b1.w));
            union { s16x8 v; unsigned short u[8]; } H, L;
#pragma unroll
            for (int jj = 0; jj < 8; ++jj) {
                H.u[jj] = f32_to_bf16(t[jj]);
                L.u[jj] = f32_to_bf16(t[jj] - bf16_to_f32(H.u[jj]));
            }
            ahi[kc] = H.v; alo[kc] = L.v;
        }
    }
    __syncthreads();

    f32x16 acc[4];
#pragma unroll
    for (int nt = 0; nt < 4; ++nt)
#pragma unroll
        for (int r = 0; r < 16; ++r) acc[nt][r] = 0.f;

#pragma unroll
    for (int nt = 0; nt < 4; ++nt) {
        const unsigned short* bp = sB + (size_t)(nt * 16) * 512 + lane * 8;
#pragma unroll
        for (int kc = 0; kc < 8; ++kc) {        // Bhi rows: hi*hi + lo*hi
            s16x8 b = *(const s16x8*)(bp + kc * 512);
            acc[nt] = __builtin_amdgcn_mfma_f32_32x32x16_bf16(ahi[kc], b, acc[nt], 0, 0, 0);
            acc[nt] = __builtin_amdgcn_mfma_f32_32x32x16_bf16(alo[kc], b, acc[nt], 0, 0, 0);
        }
#pragma unroll
        for (int kc = 0; kc < 8; ++kc) {        // Blo rows: hi*lo
            s16x8 b = *(const s16x8*)(bp + (8 + kc) * 512);
            acc[nt] = __builtin_amdgcn_mfma_f32_32x32x16_bf16(ahi[kc], b, acc[nt], 0, 0, 0);
        }
    }

    // epilogue: C layout col=lane&31, row=(reg&3)+8*(reg>>2)+4*(lane>>5)
    const int rbase = row0 + w * 32 + 4 * kg;
#pragma unroll
    for (int nt = 0; nt < 4; ++nt) {
        int col = nt * 32 + nin;
        float bv = bias[col];
#pragma unroll
        for (int reg = 0; reg < 16; ++reg) {
            int gr = rbase + (reg & 3) + 8 * (reg >> 2);
            float v = acc[nt][reg] + bv;
            if (RELU) v = fmaxf(v, 0.f);
            if (gr < NT) C[(size_t)gr * 128 + col] = v;
            acc[nt][reg] = (gr < NT) ? v : 0.f;  // masked value for stats
        }
    }

    if (STATS) {
        __syncthreads();               // B reads done; reuse LDS for stats
        float* ls = (float*)smem;
        ls[tid] = 0.f;
        __syncthreads();
#pragma unroll
        for (int nt = 0; nt < 4; ++nt) {
            int col = nt * 32 + nin;
            float s = 0.f, q = 0.f;
#pragma unroll
            for (int reg = 0; reg < 16; ++reg) { float v = acc[nt][reg]; s += v; q += v * v; }
            atomicAdd(&ls[col], s);
            atomicAdd(&ls[128 + col], q);
        }
        __syncthreads();
        if (tid < 128) {
            atomicAdd(&gsum[tid], ls[tid]);
            atomicAdd(&gsumsq[tid], ls[128 + tid]);
        }
    }
}

// ---------------------------------------------------------------------------
// BN parameter fold: bn_a = gamma*rsqrt(var+eps), bn_b = beta - mu*bn_a
// ---------------------------------------------------------------------------
__global__ __launch_bounds__(128) void bnparam_kernel(const float* __restrict__ gsum,
                                                      const float* __restrict__ gsumsq,
                                                      const float* __restrict__ gamma,
                                                      const float* __restrict__ beta,
                                                      float* __restrict__ bn_a,
                                                      float* __restrict__ bn_b) {
    int c = threadIdx.x;
    float mu = gsum[c] * (1.0f / NT);
    float var = gsumsq[c] * (1.0f / NT) - mu * mu;
    float inv = rsqrtf(var + 1e-5f);
    float a = gamma[c] * inv;
    bn_a[c] = a;
    bn_b[c] = beta[c] - mu * a;
}

// ---------------------------------------------------------------------------
// Per-graph readout: hg[g, colOff + c] = sum over nodes of graph g of h[n, c]
// ---------------------------------------------------------------------------
__global__ __launch_bounds__(256) void readout_kernel(const float* __restrict__ h,
                                                      const int* __restrict__ goff,
                                                      float* __restrict__ hg,
                                                      int colOff) {
    int g = blockIdx.x;
    int c = threadIdx.x & 127;
    int half = threadIdx.x >> 7;
    int beg = goff[g], end = goff[g + 1];
    float acc = 0.f;
    for (int n = beg + half; n < end; n += 2) acc += h[(size_t)n * 128 + c];
    __shared__ float ls[256];
    ls[threadIdx.x] = acc;
    __syncthreads();
    if (threadIdx.x < 128) hg[g * 256 + colOff + c] = ls[c] + ls[128 + c];
}

// ---------------------------------------------------------------------------
// Output MLP: out[g] = relu(relu(hg@oW1+ob1)@oW2+ob2)@oW3+ob3
// ---------------------------------------------------------------------------
__global__ __launch_bounds__(128) void mlp_kernel(const float* __restrict__ hg,
                                                  const float* __restrict__ oW1,
                                                  const float* __restrict__ ob1,
                                                  const float* __restrict__ oW2,
                                                  const float* __restrict__ ob2,
                                                  const float* __restrict__ oW3,
                                                  const float* __restrict__ ob3,
                                                  float* __restrict__ out) {
    int g = blockIdx.x, t = threadIdx.x;
    __shared__ float sh[256];
    __shared__ float z[128];
    sh[t] = hg[g * 256 + t];
    sh[t + 128] = hg[g * 256 + 128 + t];
    __syncthreads();
    float acc = ob1[t];
    for (int k = 0; k < 256; ++k) acc = fmaf(sh[k], oW1[k * 128 + t], acc);
    float z1 = fmaxf(acc, 0.f);
    z[t] = z1;
    __syncthreads();
    acc = ob2[t];
    for (int k = 0; k < 128; ++k) acc = fmaf(z[k], oW2[k * 128 + t], acc);
    float z2 = fmaxf(acc, 0.f);
    float p = z2 * oW3[t];
    for (int off = 32; off > 0; off >>= 1) p += __shfl_down(p, off, 64);
    __shared__ float wsum[2];
    if ((t & 63) == 0) wsum[t >> 6] = p;
    __syncthreads();
    if (t == 0) out[g] = wsum[0] + wsum[1] + ob3[0];
}

// ---------------------------------------------------------------------------
extern "C" void kernel_launch(void* const* d_in, const int* in_sizes, int n_in,
                              void* d_out, int out_size, void* d_ws, size_t ws_size,
                              hipStream_t stream) {
    (void)in_sizes; (void)n_in; (void)out_size; (void)ws_size;
    const float* feats = (const float*)d_in[0];
    const int*   src   = (const int*)d_in[1];
    const int*   dst   = (const int*)d_in[2];
    const int*   gid   = (const int*)d_in[3];
    const float* epsp  = (const float*)d_in[5];
    const float* Wa    = (const float*)d_in[6];
    const float* ba    = (const float*)d_in[7];
    const float* bng   = (const float*)d_in[8];
    const float* bnb   = (const float*)d_in[9];
    const float* Wb    = (const float*)d_in[10];
    const float* bb    = (const float*)d_in[11];
    const float* oW1   = (const float*)d_in[12];
    const float* ob1   = (const float*)d_in[13];
    const float* oW2   = (const float*)d_in[14];
    const float* ob2   = (const float*)d_in[15];
    const float* oW3   = (const float*)d_in[16];
    const float* ob3   = (const float*)d_in[17];
    float* out = (float*)d_out;

    char* p = (char*)d_ws;
    auto carve = [&](size_t bytes) -> void* {
        void* r = (void*)p;
        p += (bytes + 255) & ~(size_t)255;
        return r;
    };
    unsigned short* Asplit = (unsigned short*)carve((size_t)NT * 256 * 2);
    float* bufY    = (float*)carve((size_t)NT * DIM * 4);
    float* bufH    = (float*)carve((size_t)NT * DIM * 4);
    unsigned short* Bfrag = (unsigned short*)carve((size_t)8 * 32768 * 2);
    int*   esrc    = (int*)carve((size_t)NE * 4);
    // counts and cursor MUST be one contiguous carve (single fused memset).
    int*   counts  = (int*)carve((size_t)NT * 2 * 4);
    int*   cursor  = counts + NT;
    int*   indptr  = (int*)carve((size_t)(NT + 1) * 4);
    int*   bsums   = (int*)carve((size_t)SCAN_B * 4);
    int*   boffs   = (int*)carve((size_t)SCAN_B * 4);
    int*   goff    = (int*)carve((size_t)(NG + 1) * 4);
    float* gsum    = (float*)carve(2 * 128 * 4);   // gsum+gsumsq contiguous
    float* gsumsq  = gsum + 128;
    float* bn_a    = (float*)carve(128 * 4);
    float* bn_b    = (float*)carve(128 * 4);
    float* hg      = (float*)carve((size_t)NG * 256 * 4);

    const int EB = (NE + 255) / 256;

    ranges_kernel<<<1, 256, 0, stream>>>(gid, goff);
    bsplit_kernel<<<64, 256, 0, stream>>>(Wa, Wb, Bfrag);

    for (int e = 0; e < 2; ++e) {
        hipMemsetAsync(counts, 0, (size_t)NT * 2 * 4, stream);
        hist_kernel<<<EB, 256, 0, stream>>>(dst + e * NE, counts);
        scanA_kernel<<<SCAN_B, 256, 0, stream>>>(counts, bsums);
        scanB_kernel<<<1, 256, 0, stream>>>(bsums, boffs);
        scanC_kernel<<<SCAN_B, 256, 0, stream>>>(counts, boffs, indptr);
        fill_kernel<<<EB, 256, 0, stream>>>(src + e * NE, dst + e * NE, indptr,
                                            cursor, esrc);
        const float* hIn = feats;
        for (int l = 0; l < 2; ++l) {
            int wi = e * 2 + l;
            agg_split_kernel<<<(NT + 7) / 8, 256, 0, stream>>>(hIn, indptr, esrc,
                                                               epsp, wi, Asplit);
            hipMemsetAsync(gsum, 0, 2 * 128 * 4, stream);
            mfma_gemm_kernel<0, 1, 0><<<GEMM_B, 256, 0, stream>>>(
                Asplit, Bfrag + (size_t)wi * 32768, ba + (size_t)wi * DIM,
                nullptr, nullptr, bufY, gsum, gsumsq);
            bnparam_kernel<<<1, 128, 0, stream>>>(gsum, gsumsq,
                                                  bng + (size_t)wi * DIM,
                                                  bnb + (size_t)wi * DIM,
                                                  bn_a, bn_b);
            if (l == 0)
                mfma_gemm_kernel<1, 0, 1><<<GEMM_B, 256, 0, stream>>>(
                    bufY, Bfrag + (size_t)(4 + wi) * 32768, bb + (size_t)wi * DIM,
                    bn_a, bn_b, bufH, nullptr, nullptr);
            else
                mfma_gemm_kernel<1, 0, 0><<<GEMM_B, 256, 0, stream>>>(
                    bufY, Bfrag + (size_t)(4 + wi) * 32768, bb + (size_t)wi * DIM,
                    bn_a, bn_b, bufH, nullptr, nullptr);
            hIn = bufH;
        }
        readout_kernel<<<NG, 256, 0, stream>>>(bufH, goff, hg, e * 128);
    }
    mlp_kernel<<<NG, 128, 0, stream>>>(hg, oW1, ob1, oW2, ob2, oW3, ob3, out);
}

// Round 5
// 723.187 us; speedup vs baseline: 1.6101x; 1.0795x over previous
//
#include <hip/hip_runtime.h>

#define NT 50000   // nodes
#define NE 800000  // edges per edge-type
#define NG 256     // graphs
#define DIM 128
#define SCAN_B ((NT + 255) / 256)    // 196 scan blocks
#define GEMM_B ((NT + 127) / 128)    // 391 MFMA-GEMM blocks

typedef short s16x8 __attribute__((ext_vector_type(8)));
typedef float f32x16 __attribute__((ext_vector_type(16)));

__device__ __forceinline__ unsigned short f32_to_bf16(float f) {
    unsigned int u = __float_as_uint(f);
    u += 0x7FFFu + ((u >> 16) & 1u);   // round-to-nearest-even
    return (unsigned short)(u >> 16);
}
__device__ __forceinline__ float bf16_to_f32(unsigned short h) {
    return __uint_as_float(((unsigned int)h) << 16);
}

// ---------------------------------------------------------------------------
// Graph ranges: goff[g] = lower_bound(graph_ids, g); graph_ids is sorted.
// ---------------------------------------------------------------------------
__global__ __launch_bounds__(256) void ranges_kernel(const int* __restrict__ gid,
                                                     int* __restrict__ goff) {
    int g = threadIdx.x;
    int lo = 0, hi = NT;
    while (lo < hi) {
        int mid = (lo + hi) >> 1;
        if (gid[mid] < g) lo = mid + 1; else hi = mid;
    }
    goff[g] = lo;
    if (g == 0) goff[NG] = NT;
}

// ---------------------------------------------------------------------------
// fp32 -> bf16 mirror (for the neighbor-gather path only)
// ---------------------------------------------------------------------------
__global__ __launch_bounds__(256) void tobf16_kernel(const float* __restrict__ in,
                                                     unsigned short* __restrict__ out) {
    int i = blockIdx.x * 256 + threadIdx.x;   // float4 index, NT*32 total
    if (i >= NT * 32) return;
    float4 v = ((const float4*)in)[i];
    ushort4 o;
    o.x = f32_to_bf16(v.x); o.y = f32_to_bf16(v.y);
    o.z = f32_to_bf16(v.z); o.w = f32_to_bf16(v.w);
    ((ushort4*)out)[i] = o;
}

// ---------------------------------------------------------------------------
// CSR build by dst: histogram -> 3-phase exclusive scan -> fill
// ---------------------------------------------------------------------------
__global__ __launch_bounds__(256) void hist_kernel(const int* __restrict__ dst,
                                                   int* __restrict__ counts) {
    int i = blockIdx.x * 256 + threadIdx.x;
    if (i < NE) atomicAdd(&counts[dst[i]], 1);
}

__global__ __launch_bounds__(256) void scanA_kernel(const int* __restrict__ counts,
                                                    int* __restrict__ blockSums) {
    __shared__ int ls[256];
    int i = blockIdx.x * 256 + threadIdx.x;
    ls[threadIdx.x] = (i < NT) ? counts[i] : 0;
    __syncthreads();
#pragma unroll
    for (int off = 128; off > 0; off >>= 1) {
        if (threadIdx.x < off) ls[threadIdx.x] += ls[threadIdx.x + off];
        __syncthreads();
    }
    if (threadIdx.x == 0) blockSums[blockIdx.x] = ls[0];
}

__global__ __launch_bounds__(256) void scanB_kernel(const int* __restrict__ blockSums,
                                                    int* __restrict__ blockOffs) {
    __shared__ int ls[256];
    int t = threadIdx.x;
    int own = (t < SCAN_B) ? blockSums[t] : 0;
    ls[t] = own;
    __syncthreads();
#pragma unroll
    for (int off = 1; off < 256; off <<= 1) {
        int v = (t >= off) ? ls[t - off] : 0;
        __syncthreads();
        ls[t] += v;
        __syncthreads();
    }
    if (t < SCAN_B) blockOffs[t] = ls[t] - own;
}

__global__ __launch_bounds__(256) void scanC_kernel(const int* __restrict__ counts,
                                                    const int* __restrict__ blockOffs,
                                                    int* __restrict__ indptr) {
    __shared__ int ls[256];
    int t = threadIdx.x;
    int i = blockIdx.x * 256 + t;
    int own = (i < NT) ? counts[i] : 0;
    ls[t] = own;
    __syncthreads();
#pragma unroll
    for (int off = 1; off < 256; off <<= 1) {
        int v = (t >= off) ? ls[t - off] : 0;
        __syncthreads();
        ls[t] += v;
        __syncthreads();
    }
    if (i < NT) indptr[i] = blockOffs[blockIdx.x] + ls[t] - own;
    if (i == 0) indptr[NT] = NE;
}

__global__ __launch_bounds__(256) void fill_kernel(const int* __restrict__ src,
                                                   const int* __restrict__ dst,
                                                   const int* __restrict__ indptr,
                                                   int* __restrict__ cursor,
                                                   int* __restrict__ esrc) {
    int i = blockIdx.x * 256 + threadIdx.x;
    if (i < NE) {
        int d = dst[i];
        int pos = atomicAdd(&cursor[d], 1);
        esrc[indptr[d] + pos] = src[i];
    }
}

// ---------------------------------------------------------------------------
// Aggregation + bf16 hi/lo split: x[n] = (1+eps)*h[n] + sum hb[esrc[j]]
// Self term from fp32 h (1 read/node); neighbors gathered from bf16 mirror
// (256B/row, 4-deep unrolled for latency). Output: [hi(128)|lo(128)] bf16.
// ---------------------------------------------------------------------------
__global__ __launch_bounds__(256) void agg_split_kernel(
        const float* __restrict__ h,
        const unsigned short* __restrict__ hb,
        const int* __restrict__ indptr, const int* __restrict__ esrc,
        const float* __restrict__ eps_p, int eps_idx,
        unsigned short* __restrict__ xout) {
    int node = blockIdx.x * 8 + (threadIdx.x >> 5);
    int lane = threadIdx.x & 31;             // cols 4*lane .. 4*lane+3
    if (node >= NT) return;
    float e1 = 1.0f + eps_p[eps_idx];
    float4 a = ((const float4*)h)[(size_t)node * 32 + lane];
    float s0 = e1 * a.x, s1 = e1 * a.y, s2 = e1 * a.z, s3 = e1 * a.w;
    int beg = indptr[node], end = indptr[node + 1];
    int j = beg;
    for (; j + 4 <= end; j += 4) {
        int i0 = esrc[j], i1 = esrc[j + 1], i2 = esrc[j + 2], i3 = esrc[j + 3];
        ushort4 v0 = *(const ushort4*)(hb + (size_t)i0 * 128 + lane * 4);
        ushort4 v1 = *(const ushort4*)(hb + (size_t)i1 * 128 + lane * 4);
        ushort4 v2 = *(const ushort4*)(hb + (size_t)i2 * 128 + lane * 4);
        ushort4 v3 = *(const ushort4*)(hb + (size_t)i3 * 128 + lane * 4);
        s0 += bf16_to_f32(v0.x) + bf16_to_f32(v1.x) + bf16_to_f32(v2.x) + bf16_to_f32(v3.x);
        s1 += bf16_to_f32(v0.y) + bf16_to_f32(v1.y) + bf16_to_f32(v2.y) + bf16_to_f32(v3.y);
        s2 += bf16_to_f32(v0.z) + bf16_to_f32(v1.z) + bf16_to_f32(v2.z) + bf16_to_f32(v3.z);
        s3 += bf16_to_f32(v0.w) + bf16_to_f32(v1.w) + bf16_to_f32(v2.w) + bf16_to_f32(v3.w);
    }
    for (; j < end; ++j) {
        ushort4 v0 = *(const ushort4*)(hb + (size_t)esrc[j] * 128 + lane * 4);
        s0 += bf16_to_f32(v0.x); s1 += bf16_to_f32(v0.y);
        s2 += bf16_to_f32(v0.z); s3 += bf16_to_f32(v0.w);
    }
    ushort4 hv, lv;
    hv.x = f32_to_bf16(s0); lv.x = f32_to_bf16(s0 - bf16_to_f32(hv.x));
    hv.y = f32_to_bf16(s1); lv.y = f32_to_bf16(s1 - bf16_to_f32(hv.y));
    hv.z = f32_to_bf16(s2); lv.z = f32_to_bf16(s2 - bf16_to_f32(hv.z));
    hv.w = f32_to_bf16(s3); lv.w = f32_to_bf16(s3 - bf16_to_f32(hv.w));
    *(ushort4*)(xout + (size_t)node * 256 + lane * 4) = hv;
    *(ushort4*)(xout + (size_t)node * 256 + 128 + lane * 4) = lv;
}

// ---------------------------------------------------------------------------
// Weight split + frag-major repack (see R4 comment).
// ---------------------------------------------------------------------------
__global__ __launch_bounds__(256) void bsplit_kernel(const float* __restrict__ Wa,
                                                     const float* __restrict__ Wb,
                                                     unsigned short* __restrict__ Bfrag) {
    int slot = blockIdx.x >> 3;
    int sub = blockIdx.x & 7;
    const float* W = (slot < 4) ? (Wa + (size_t)slot * DIM * DIM)
                                : (Wb + (size_t)(slot - 4) * DIM * DIM);
    unsigned short* out = Bfrag + (size_t)slot * 32768;
    for (int i = 0; i < 16; ++i) {
        int e = sub * 4096 + i * 256 + threadIdx.x;
        int kphys = e >> 7, n = e & 127;
        int k = kphys & 127;
        float wv = W[k * 128 + n];
        unsigned short hi = f32_to_bf16(wv);
        unsigned short val = (kphys < 128) ? hi : f32_to_bf16(wv - bf16_to_f32(hi));
        int nt = n >> 5, nin = n & 31;
        int kcp = kphys >> 4, kgp = (kphys >> 3) & 1, jj = kphys & 7;
        out[(size_t)(((nt * 16 + kcp) * 64) + kgp * 32 + nin) * 8 + jj] = val;
    }
}

// ---------------------------------------------------------------------------
// MFMA GEMM (3-term bf16 split). See R4 comment for layout details.
// ---------------------------------------------------------------------------
template <int SRC_FP32, int STATS, int RELU>
__global__ __launch_bounds__(256) void mfma_gemm_kernel(
        const void* __restrict__ Asrc,
        const unsigned short* __restrict__ Bfrag,
        const float* __restrict__ bias,
        const float* __restrict__ bn_a, const float* __restrict__ bn_b,
        float* __restrict__ C,
        float* __restrict__ gsum, float* __restrict__ gsumsq) {
    __shared__ char smem[65536];
    unsigned short* sB = (unsigned short*)smem;
    const int tid = threadIdx.x;
    const int w = tid >> 6, lane = tid & 63;
    const int nin = lane & 31, kg = lane >> 5;
    const int row0 = blockIdx.x * 128;
    const int myrow = row0 + w * 32 + nin;
    const int rowc = myrow < NT ? myrow : NT - 1;

    {
        const uint4* Bg = (const uint4*)Bfrag;
        uint4* sB4 = (uint4*)smem;
#pragma unroll
        for (int i = 0; i < 16; ++i) sB4[tid + 256 * i] = Bg[tid + 256 * i];
    }

    s16x8 ahi[8], alo[8];
    if (!SRC_FP32) {
        const unsigned short* ar = (const unsigned short*)Asrc + (size_t)rowc * 256 + kg * 8;
#pragma unroll
        for (int kc = 0; kc < 8; ++kc) {
            ahi[kc] = *(const s16x8*)(ar + kc * 16);
            alo[kc] = *(const s16x8*)(ar + 128 + kc * 16);
        }
    } else {
        const float* yr = (const float*)Asrc + (size_t)rowc * 128 + kg * 8;
#pragma unroll
        for (int kc = 0; kc < 8; ++kc) {
            int c0 = kc * 16 + kg * 8;
            float4 y0 = *(const float4*)(yr + kc * 16);
            float4 y1 = *(const float4*)(yr + kc * 16 + 4);
            float4 a0 = *(const float4*)(bn_a + c0);
            float4 a1 = *(const float4*)(bn_a + c0 + 4);
            float4 b0 = *(const float4*)(bn_b + c0);
            float4 b1 = *(const float4*)(bn_b + c0 + 4);
            float t[8];
            t[0] = fmaxf(0.f, fmaf(y0.x, a0.x, b0.x));
            t[1] = fmaxf(0.f, fmaf(y0.y, a0.y, b0.y));
            t[2] = fmaxf(0.f, fmaf(y0.z, a0.z, b0.z));
            t[3] = fmaxf(0.f, fmaf(y0.w, a0.w, b0.w));
            t[4] = fmaxf(0.f, fmaf(y1.x, a1.x, b1.x));
            t[5] = fmaxf(0.f, fmaf(y1.y, a1.y, b1.y));
            t[6] = fmaxf(0.f, fmaf(y1.z, a1.z, b1.z));
            t[7] = fmaxf(0.f, fmaf(y1.w, a1.w, b1.w));
            union { s16x8 v; unsigned short u[8]; } H, L;
#pragma unroll
            for (int jj = 0; jj < 8; ++jj) {
                H.u[jj] = f32_to_bf16(t[jj]);
                L.u[jj] = f32_to_bf16(t[jj] - bf16_to_f32(H.u[jj]));
            }
            ahi[kc] = H.v; alo[kc] = L.v;
        }
    }
    __syncthreads();

    f32x16 acc[4];
#pragma unroll
    for (int nt = 0; nt < 4; ++nt)
#pragma unroll
        for (int r = 0; r < 16; ++r) acc[nt][r] = 0.f;

#pragma unroll
    for (int nt = 0; nt < 4; ++nt) {
        const unsigned short* bp = sB + (size_t)(nt * 16) * 512 + lane * 8;
#pragma unroll
        for (int kc = 0; kc < 8; ++kc) {
            s16x8 b = *(const s16x8*)(bp + kc * 512);
            acc[nt] = __builtin_amdgcn_mfma_f32_32x32x16_bf16(ahi[kc], b, acc[nt], 0, 0, 0);
            acc[nt] = __builtin_amdgcn_mfma_f32_32x32x16_bf16(alo[kc], b, acc[nt], 0, 0, 0);
        }
#pragma unroll
        for (int kc = 0; kc < 8; ++kc) {
            s16x8 b = *(const s16x8*)(bp + (8 + kc) * 512);
            acc[nt] = __builtin_amdgcn_mfma_f32_32x32x16_bf16(ahi[kc], b, acc[nt], 0, 0, 0);
        }
    }

    const int rbase = row0 + w * 32 + 4 * kg;
#pragma unroll
    for (int nt = 0; nt < 4; ++nt) {
        int col = nt * 32 + nin;
        float bv = bias[col];
#pragma unroll
        for (int reg = 0; reg < 16; ++reg) {
            int gr = rbase + (reg & 3) + 8 * (reg >> 2);
            float v = acc[nt][reg] + bv;
            if (RELU) v = fmaxf(v, 0.f);
            if (gr < NT) C[(size_t)gr * 128 + col] = v;
            acc[nt][reg] = (gr < NT) ? v : 0.f;
        }
    }

    if (STATS) {
        __syncthreads();
        float* ls = (float*)smem;
        ls[tid] = 0.f;
        __syncthreads();
#pragma unroll
        for (int nt = 0; nt < 4; ++nt) {
            int col = nt * 32 + nin;
            float s = 0.f, q = 0.f;
#pragma unroll
            for (int reg = 0; reg < 16; ++reg) { float v = acc[nt][reg]; s += v; q += v * v; }
            atomicAdd(&ls[col], s);
            atomicAdd(&ls[128 + col], q);
        }
        __syncthreads();
        if (tid < 128) {
            atomicAdd(&gsum[tid], ls[tid]);
            atomicAdd(&gsumsq[tid], ls[128 + tid]);
        }
    }
}

// ---------------------------------------------------------------------------
__global__ __launch_bounds__(128) void bnparam_kernel(const float* __restrict__ gsum,
                                                      const float* __restrict__ gsumsq,
                                                      const float* __restrict__ gamma,
                                                      const float* __restrict__ beta,
                                                      float* __restrict__ bn_a,
                                                      float* __restrict__ bn_b) {
    int c = threadIdx.x;
    float mu = gsum[c] * (1.0f / NT);
    float var = gsumsq[c] * (1.0f / NT) - mu * mu;
    float inv = rsqrtf(var + 1e-5f);
    float a = gamma[c] * inv;
    bn_a[c] = a;
    bn_b[c] = beta[c] - mu * a;
}

// ---------------------------------------------------------------------------
__global__ __launch_bounds__(256) void readout_kernel(const float* __restrict__ h,
                                                      const int* __restrict__ goff,
                                                      float* __restrict__ hg,
                                                      int colOff) {
    int g = blockIdx.x;
    int c = threadIdx.x & 127;
    int half = threadIdx.x >> 7;
    int beg = goff[g], end = goff[g + 1];
    float acc = 0.f;
    for (int n = beg + half; n < end; n += 2) acc += h[(size_t)n * 128 + c];
    __shared__ float ls[256];
    ls[threadIdx.x] = acc;
    __syncthreads();
    if (threadIdx.x < 128) hg[g * 256 + colOff + c] = ls[c] + ls[128 + c];
}

// ---------------------------------------------------------------------------
__global__ __launch_bounds__(128) void mlp_kernel(const float* __restrict__ hg,
                                                  const float* __restrict__ oW1,
                                                  const float* __restrict__ ob1,
                                                  const float* __restrict__ oW2,
                                                  const float* __restrict__ ob2,
                                                  const float* __restrict__ oW3,
                                                  const float* __restrict__ ob3,
                                                  float* __restrict__ out) {
    int g = blockIdx.x, t = threadIdx.x;
    __shared__ float sh[256];
    __shared__ float z[128];
    sh[t] = hg[g * 256 + t];
    sh[t + 128] = hg[g * 256 + 128 + t];
    __syncthreads();
    float acc = ob1[t];
    for (int k = 0; k < 256; ++k) acc = fmaf(sh[k], oW1[k * 128 + t], acc);
    float z1 = fmaxf(acc, 0.f);
    z[t] = z1;
    __syncthreads();
    acc = ob2[t];
    for (int k = 0; k < 128; ++k) acc = fmaf(z[k], oW2[k * 128 + t], acc);
    float z2 = fmaxf(acc, 0.f);
    float p = z2 * oW3[t];
    for (int off = 32; off > 0; off >>= 1) p += __shfl_down(p, off, 64);
    __shared__ float wsum[2];
    if ((t & 63) == 0) wsum[t >> 6] = p;
    __syncthreads();
    if (t == 0) out[g] = wsum[0] + wsum[1] + ob3[0];
}

// ---------------------------------------------------------------------------
extern "C" void kernel_launch(void* const* d_in, const int* in_sizes, int n_in,
                              void* d_out, int out_size, void* d_ws, size_t ws_size,
                              hipStream_t stream) {
    (void)in_sizes; (void)n_in; (void)out_size; (void)ws_size;
    const float* feats = (const float*)d_in[0];
    const int*   src   = (const int*)d_in[1];
    const int*   dst   = (const int*)d_in[2];
    const int*   gid   = (const int*)d_in[3];
    const float* epsp  = (const float*)d_in[5];
    const float* Wa    = (const float*)d_in[6];
    const float* ba    = (const float*)d_in[7];
    const float* bng   = (const float*)d_in[8];
    const float* bnb   = (const float*)d_in[9];
    const float* Wb    = (const float*)d_in[10];
    const float* bb    = (const float*)d_in[11];
    const float* oW1   = (const float*)d_in[12];
    const float* ob1   = (const float*)d_in[13];
    const float* oW2   = (const float*)d_in[14];
    const float* ob2   = (const float*)d_in[15];
    const float* oW3   = (const float*)d_in[16];
    const float* ob3   = (const float*)d_in[17];
    float* out = (float*)d_out;

    char* p = (char*)d_ws;
    auto carve = [&](size_t bytes) -> void* {
        void* r = (void*)p;
        p += (bytes + 255) & ~(size_t)255;
        return r;
    };
    unsigned short* Asplit = (unsigned short*)carve((size_t)NT * 256 * 2);
    float* bufY    = (float*)carve((size_t)NT * DIM * 4);
    float* bufH    = (float*)carve((size_t)NT * DIM * 4);
    unsigned short* featsB = (unsigned short*)carve((size_t)NT * DIM * 2);
    unsigned short* hB     = (unsigned short*)carve((size_t)NT * DIM * 2);
    unsigned short* Bfrag = (unsigned short*)carve((size_t)8 * 32768 * 2);
    int*   esrc    = (int*)carve((size_t)NE * 4);
    // counts and cursor MUST be one contiguous carve (single fused memset).
    int*   counts  = (int*)carve((size_t)NT * 2 * 4);
    int*   cursor  = counts + NT;
    int*   indptr  = (int*)carve((size_t)(NT + 1) * 4);
    int*   bsums   = (int*)carve((size_t)SCAN_B * 4);
    int*   boffs   = (int*)carve((size_t)SCAN_B * 4);
    int*   goff    = (int*)carve((size_t)(NG + 1) * 4);
    float* gsum    = (float*)carve(2 * 128 * 4);   // gsum+gsumsq contiguous
    float* gsumsq  = gsum + 128;
    float* bn_a    = (float*)carve(128 * 4);
    float* bn_b    = (float*)carve(128 * 4);
    float* hg      = (float*)carve((size_t)NG * 256 * 4);

    const int EB = (NE + 255) / 256;
    const int CB = (NT * 32 + 255) / 256;   // tobf16 blocks

    ranges_kernel<<<1, 256, 0, stream>>>(gid, goff);
    bsplit_kernel<<<64, 256, 0, stream>>>(Wa, Wb, Bfrag);
    tobf16_kernel<<<CB, 256, 0, stream>>>(feats, featsB);

    for (int e = 0; e < 2; ++e) {
        hipMemsetAsync(counts, 0, (size_t)NT * 2 * 4, stream);
        hist_kernel<<<EB, 256, 0, stream>>>(dst + e * NE, counts);
        scanA_kernel<<<SCAN_B, 256, 0, stream>>>(counts, bsums);
        scanB_kernel<<<1, 256, 0, stream>>>(bsums, boffs);
        scanC_kernel<<<SCAN_B, 256, 0, stream>>>(counts, boffs, indptr);
        fill_kernel<<<EB, 256, 0, stream>>>(src + e * NE, dst + e * NE, indptr,
                                            cursor, esrc);
        for (int l = 0; l < 2; ++l) {
            int wi = e * 2 + l;
            if (l == 0) {
                agg_split_kernel<<<(NT + 7) / 8, 256, 0, stream>>>(
                    feats, featsB, indptr, esrc, epsp, wi, Asplit);
            } else {
                tobf16_kernel<<<CB, 256, 0, stream>>>(bufH, hB);
                agg_split_kernel<<<(NT + 7) / 8, 256, 0, stream>>>(
                    bufH, hB, indptr, esrc, epsp, wi, Asplit);
            }
            hipMemsetAsync(gsum, 0, 2 * 128 * 4, stream);
            mfma_gemm_kernel<0, 1, 0><<<GEMM_B, 256, 0, stream>>>(
                Asplit, Bfrag + (size_t)wi * 32768, ba + (size_t)wi * DIM,
                nullptr, nullptr, bufY, gsum, gsumsq);
            bnparam_kernel<<<1, 128, 0, stream>>>(gsum, gsumsq,
                                                  bng + (size_t)wi * DIM,
                                                  bnb + (size_t)wi * DIM,
                                                  bn_a, bn_b);
            if (l == 0)
                mfma_gemm_kernel<1, 0, 1><<<GEMM_B, 256, 0, stream>>>(
                    bufY, Bfrag + (size_t)(4 + wi) * 32768, bb + (size_t)wi * DIM,
                    bn_a, bn_b, bufH, nullptr, nullptr);
            else
                mfma_gemm_kernel<1, 0, 0><<<GEMM_B, 256, 0, stream>>>(
                    bufY, Bfrag + (size_t)(4 + wi) * 32768, bb + (size_t)wi * DIM,
                    bn_a, bn_b, bufH, nullptr, nullptr);
        }
        readout_kernel<<<NG, 256, 0, stream>>>(bufH, goff, hg, e * 128);
    }
    mlp_kernel<<<NG, 128, 0, stream>>>(hg, oW1, ob1, oW2, ob2, oW3, ob3, out);
}

// Round 6
// 669.502 us; speedup vs baseline: 1.7392x; 1.0802x over previous
//
#include <hip/hip_runtime.h>

#define NT 50000   // nodes
#define NE 800000  // edges per edge-type
#define NG 256     // graphs
#define DIM 128
#define GEMM_B ((NT + 127) / 128)    // 391 MFMA-GEMM blocks

// CSR-build partition constants
#define NB 128                        // coarse dst buckets
#define BW 391                        // bucket width: 128*391 = 50048 >= NT
#define PB 196                        // partition blocks
#define PCH 4096                      // edges per partition block: 196*4096 >= NE
#define HCN (NB * PB)                 // 25088 (bucket-major counts)

typedef short s16x8 __attribute__((ext_vector_type(8)));
typedef float f32x16 __attribute__((ext_vector_type(16)));

__device__ __forceinline__ unsigned short f32_to_bf16(float f) {
    unsigned int u = __float_as_uint(f);
    u += 0x7FFFu + ((u >> 16) & 1u);   // round-to-nearest-even
    return (unsigned short)(u >> 16);
}
__device__ __forceinline__ float bf16_to_f32(unsigned short h) {
    return __uint_as_float(((unsigned int)h) << 16);
}

// ---------------------------------------------------------------------------
// Graph ranges: goff[g] = lower_bound(graph_ids, g); graph_ids is sorted.
// ---------------------------------------------------------------------------
__global__ __launch_bounds__(256) void ranges_kernel(const int* __restrict__ gid,
                                                     int* __restrict__ goff) {
    int g = threadIdx.x;
    int lo = 0, hi = NT;
    while (lo < hi) {
        int mid = (lo + hi) >> 1;
        if (gid[mid] < g) lo = mid + 1; else hi = mid;
    }
    goff[g] = lo;
    if (g == 0) goff[NG] = NT;
}

// ---------------------------------------------------------------------------
// fp32 -> bf16 mirror (neighbor-gather path; feats only — layer outputs get
// their bf16 mirror from the GEMM epilogue)
// ---------------------------------------------------------------------------
__global__ __launch_bounds__(256) void tobf16_kernel(const float* __restrict__ in,
                                                     unsigned short* __restrict__ out) {
    int i = blockIdx.x * 256 + threadIdx.x;   // float4 index, NT*32 total
    if (i >= NT * 32) return;
    float4 v = ((const float4*)in)[i];
    ushort4 o;
    o.x = f32_to_bf16(v.x); o.y = f32_to_bf16(v.y);
    o.z = f32_to_bf16(v.z); o.w = f32_to_bf16(v.w);
    ((ushort4*)out)[i] = o;
}

// ---------------------------------------------------------------------------
// CSR build, 2-level counting sort (no global atomics, no write-amplification)
// K1: per-block LDS histogram over NB coarse buckets -> hcoarse[bucket][block]
// ---------------------------------------------------------------------------
__global__ __launch_bounds__(256) void csr_part_hist_kernel(
        const int* __restrict__ dst, int* __restrict__ hcoarse) {
    __shared__ int h[NB];
    if (threadIdx.x < NB) h[threadIdx.x] = 0;
    __syncthreads();
#pragma unroll
    for (int i = 0; i < PCH / 256; ++i) {
        int e = blockIdx.x * PCH + i * 256 + threadIdx.x;
        if (e < NE) atomicAdd(&h[dst[e] / BW], 1);
    }
    __syncthreads();
    if (threadIdx.x < NB)
        hcoarse[threadIdx.x * PB + blockIdx.x] = h[threadIdx.x];
}

// K2: exclusive scan of hcoarse (bucket-major) -> off; bucketBase; indptr[NT]
__global__ __launch_bounds__(1024) void csr_scan_kernel(
        const int* __restrict__ hcoarse, int* __restrict__ off,
        int* __restrict__ bucketBase, int* __restrict__ indptr) {
    __shared__ int ps[1024];
    int t = threadIdx.x;
    const int CH = (HCN + 1023) / 1024;  // 25
    int beg = t * CH, end = beg + CH; if (end > HCN) end = HCN;
    int s = 0;
    for (int i = beg; i < end; ++i) s += hcoarse[i];
    ps[t] = s;
    __syncthreads();
    for (int o = 1; o < 1024; o <<= 1) {
        int v = (t >= o) ? ps[t - o] : 0;
        __syncthreads();
        ps[t] += v;
        __syncthreads();
    }
    int run = (t == 0) ? 0 : ps[t - 1];
    for (int i = beg; i < end; ++i) {
        off[i] = run;
        if (i % PB == 0) bucketBase[i / PB] = run;
        run += hcoarse[i];
    }
    if (t == 1023) bucketBase[NB] = NE;
    if (t == 0) indptr[NT] = NE;
}

// K3: partition edges into bucket-major packed array ((dstLocal<<16)|src)
__global__ __launch_bounds__(256) void csr_scatter_kernel(
        const int* __restrict__ src, const int* __restrict__ dst,
        const int* __restrict__ off, unsigned int* __restrict__ part) {
    __shared__ int cur[NB];
    if (threadIdx.x < NB) cur[threadIdx.x] = off[threadIdx.x * PB + blockIdx.x];
    __syncthreads();
#pragma unroll
    for (int i = 0; i < PCH / 256; ++i) {
        int e = blockIdx.x * PCH + i * 256 + threadIdx.x;
        if (e < NE) {
            int d = dst[e];
            int b = d / BW;
            int pos = atomicAdd(&cur[b], 1);
            part[pos] = ((unsigned int)(d - b * BW) << 16) | (unsigned int)src[e];
        }
    }
}

// K4: per-bucket finalize: per-node hist + scan -> indptr, then place esrc.
// All scattered writes confined to one bucket's 25KB region (one CU).
__global__ __launch_bounds__(256) void csr_finalize_kernel(
        const unsigned int* __restrict__ part, const int* __restrict__ bucketBase,
        int* __restrict__ indptr, int* __restrict__ esrc) {
    __shared__ int cnt[512];
    __shared__ int excl[512];
    __shared__ int ps[256];
    __shared__ int cur[BW + 1];
    int b = blockIdx.x, t = threadIdx.x;
    int base = bucketBase[b];
    int n = bucketBase[b + 1] - base;
    cnt[t] = 0; cnt[t + 256] = 0;
    for (int j = t; j <= BW; j += 256) cur[j] = 0;
    __syncthreads();
    for (int i = t; i < n; i += 256) atomicAdd(&cnt[part[base + i] >> 16], 1);
    __syncthreads();
    // exclusive scan of cnt[0..511]: thread t owns elements 2t, 2t+1
    int a0 = cnt[2 * t], a1 = cnt[2 * t + 1];
    ps[t] = a0 + a1;
    __syncthreads();
    for (int o = 1; o < 256; o <<= 1) {
        int v = (t >= o) ? ps[t - o] : 0;
        __syncthreads();
        ps[t] += v;
        __syncthreads();
    }
    int before = (t == 0) ? 0 : ps[t - 1];
    excl[2 * t] = before;
    excl[2 * t + 1] = before + a0;
    __syncthreads();
    int node0 = b * BW;
    for (int j = t; j < BW; j += 256) {
        int gn = node0 + j;
        if (gn < NT) indptr[gn] = base + excl[j];
    }
    for (int i = t; i < n; i += 256) {
        unsigned int pk = part[base + i];
        int dl = pk >> 16;
        int pos = atomicAdd(&cur[dl], 1);
        esrc[base + excl[dl] + pos] = (int)(pk & 0xFFFFu);
    }
}

// ---------------------------------------------------------------------------
// Aggregation + bf16 hi/lo split: x[n] = (1+eps)*h[n] + sum hb[esrc[j]]
// ---------------------------------------------------------------------------
__global__ __launch_bounds__(256) void agg_split_kernel(
        const float* __restrict__ h,
        const unsigned short* __restrict__ hb,
        const int* __restrict__ indptr, const int* __restrict__ esrc,
        const float* __restrict__ eps_p, int eps_idx,
        unsigned short* __restrict__ xout) {
    int node = blockIdx.x * 8 + (threadIdx.x >> 5);
    int lane = threadIdx.x & 31;
    if (node >= NT) return;
    float e1 = 1.0f + eps_p[eps_idx];
    float4 a = ((const float4*)h)[(size_t)node * 32 + lane];
    float s0 = e1 * a.x, s1 = e1 * a.y, s2 = e1 * a.z, s3 = e1 * a.w;
    int beg = indptr[node], end = indptr[node + 1];
    int j = beg;
    for (; j + 4 <= end; j += 4) {
        int i0 = esrc[j], i1 = esrc[j + 1], i2 = esrc[j + 2], i3 = esrc[j + 3];
        ushort4 v0 = *(const ushort4*)(hb + (size_t)i0 * 128 + lane * 4);
        ushort4 v1 = *(const ushort4*)(hb + (size_t)i1 * 128 + lane * 4);
        ushort4 v2 = *(const ushort4*)(hb + (size_t)i2 * 128 + lane * 4);
        ushort4 v3 = *(const ushort4*)(hb + (size_t)i3 * 128 + lane * 4);
        s0 += bf16_to_f32(v0.x) + bf16_to_f32(v1.x) + bf16_to_f32(v2.x) + bf16_to_f32(v3.x);
        s1 += bf16_to_f32(v0.y) + bf16_to_f32(v1.y) + bf16_to_f32(v2.y) + bf16_to_f32(v3.y);
        s2 += bf16_to_f32(v0.z) + bf16_to_f32(v1.z) + bf16_to_f32(v2.z) + bf16_to_f32(v3.z);
        s3 += bf16_to_f32(v0.w) + bf16_to_f32(v1.w) + bf16_to_f32(v2.w) + bf16_to_f32(v3.w);
    }
    for (; j < end; ++j) {
        ushort4 v0 = *(const ushort4*)(hb + (size_t)esrc[j] * 128 + lane * 4);
        s0 += bf16_to_f32(v0.x); s1 += bf16_to_f32(v0.y);
        s2 += bf16_to_f32(v0.z); s3 += bf16_to_f32(v0.w);
    }
    ushort4 hv, lv;
    hv.x = f32_to_bf16(s0); lv.x = f32_to_bf16(s0 - bf16_to_f32(hv.x));
    hv.y = f32_to_bf16(s1); lv.y = f32_to_bf16(s1 - bf16_to_f32(hv.y));
    hv.z = f32_to_bf16(s2); lv.z = f32_to_bf16(s2 - bf16_to_f32(hv.z));
    hv.w = f32_to_bf16(s3); lv.w = f32_to_bf16(s3 - bf16_to_f32(hv.w));
    *(ushort4*)(xout + (size_t)node * 256 + lane * 4) = hv;
    *(ushort4*)(xout + (size_t)node * 256 + 128 + lane * 4) = lv;
}

// ---------------------------------------------------------------------------
// Weight split + frag-major repack (see R4 comment).
// ---------------------------------------------------------------------------
__global__ __launch_bounds__(256) void bsplit_kernel(const float* __restrict__ Wa,
                                                     const float* __restrict__ Wb,
                                                     unsigned short* __restrict__ Bfrag) {
    int slot = blockIdx.x >> 3;
    int sub = blockIdx.x & 7;
    const float* W = (slot < 4) ? (Wa + (size_t)slot * DIM * DIM)
                                : (Wb + (size_t)(slot - 4) * DIM * DIM);
    unsigned short* out = Bfrag + (size_t)slot * 32768;
    for (int i = 0; i < 16; ++i) {
        int e = sub * 4096 + i * 256 + threadIdx.x;
        int kphys = e >> 7, n = e & 127;
        int k = kphys & 127;
        float wv = W[k * 128 + n];
        unsigned short hi = f32_to_bf16(wv);
        unsigned short val = (kphys < 128) ? hi : f32_to_bf16(wv - bf16_to_f32(hi));
        int nt = n >> 5, nin = n & 31;
        int kcp = kphys >> 4, kgp = (kphys >> 3) & 1, jj = kphys & 7;
        out[(size_t)(((nt * 16 + kcp) * 64) + kgp * 32 + nin) * 8 + jj] = val;
    }
}

// ---------------------------------------------------------------------------
// MFMA GEMM (3-term bf16 split). EMITB: also write bf16 mirror of C.
// ---------------------------------------------------------------------------
template <int SRC_FP32, int STATS, int RELU, int EMITB>
__global__ __launch_bounds__(256) void mfma_gemm_kernel(
        const void* __restrict__ Asrc,
        const unsigned short* __restrict__ Bfrag,
        const float* __restrict__ bias,
        const float* __restrict__ bn_a, const float* __restrict__ bn_b,
        float* __restrict__ C, unsigned short* __restrict__ CB,
        float* __restrict__ gsum, float* __restrict__ gsumsq) {
    __shared__ char smem[65536];
    unsigned short* sB = (unsigned short*)smem;
    const int tid = threadIdx.x;
    const int w = tid >> 6, lane = tid & 63;
    const int nin = lane & 31, kg = lane >> 5;
    const int row0 = blockIdx.x * 128;
    const int myrow = row0 + w * 32 + nin;
    const int rowc = myrow < NT ? myrow : NT - 1;

    {
        const uint4* Bg = (const uint4*)Bfrag;
        uint4* sB4 = (uint4*)smem;
#pragma unroll
        for (int i = 0; i < 16; ++i) sB4[tid + 256 * i] = Bg[tid + 256 * i];
    }

    s16x8 ahi[8], alo[8];
    if (!SRC_FP32) {
        const unsigned short* ar = (const unsigned short*)Asrc + (size_t)rowc * 256 + kg * 8;
#pragma unroll
        for (int kc = 0; kc < 8; ++kc) {
            ahi[kc] = *(const s16x8*)(ar + kc * 16);
            alo[kc] = *(const s16x8*)(ar + 128 + kc * 16);
        }
    } else {
        const float* yr = (const float*)Asrc + (size_t)rowc * 128 + kg * 8;
#pragma unroll
        for (int kc = 0; kc < 8; ++kc) {
            int c0 = kc * 16 + kg * 8;
            float4 y0 = *(const float4*)(yr + kc * 16);
            float4 y1 = *(const float4*)(yr + kc * 16 + 4);
            float4 a0 = *(const float4*)(bn_a + c0);
            float4 a1 = *(const float4*)(bn_a + c0 + 4);
            float4 b0 = *(const float4*)(bn_b + c0);
            float4 b1 = *(const float4*)(bn_b + c0 + 4);
            float t[8];
            t[0] = fmaxf(0.f, fmaf(y0.x, a0.x, b0.x));
            t[1] = fmaxf(0.f, fmaf(y0.y, a0.y, b0.y));
            t[2] = fmaxf(0.f, fmaf(y0.z, a0.z, b0.z));
            t[3] = fmaxf(0.f, fmaf(y0.w, a0.w, b0.w));
            t[4] = fmaxf(0.f, fmaf(y1.x, a1.x, b1.x));
            t[5] = fmaxf(0.f, fmaf(y1.y, a1.y, b1.y));
            t[6] = fmaxf(0.f, fmaf(y1.z, a1.z, b1.z));
            t[7] = fmaxf(0.f, fmaf(y1.w, a1.w, b1.w));
            union { s16x8 v; unsigned short u[8]; } H, L;
#pragma unroll
            for (int jj = 0; jj < 8; ++jj) {
                H.u[jj] = f32_to_bf16(t[jj]);
                L.u[jj] = f32_to_bf16(t[jj] - bf16_to_f32(H.u[jj]));
            }
            ahi[kc] = H.v; alo[kc] = L.v;
        }
    }
    __syncthreads();

    f32x16 acc[4];
#pragma unroll
    for (int nt = 0; nt < 4; ++nt)
#pragma unroll
        for (int r = 0; r < 16; ++r) acc[nt][r] = 0.f;

#pragma unroll
    for (int nt = 0; nt < 4; ++nt) {
        const unsigned short* bp = sB + (size_t)(nt * 16) * 512 + lane * 8;
#pragma unroll
        for (int kc = 0; kc < 8; ++kc) {
            s16x8 b = *(const s16x8*)(bp + kc * 512);
            acc[nt] = __builtin_amdgcn_mfma_f32_32x32x16_bf16(ahi[kc], b, acc[nt], 0, 0, 0);
            acc[nt] = __builtin_amdgcn_mfma_f32_32x32x16_bf16(alo[kc], b, acc[nt], 0, 0, 0);
        }
#pragma unroll
        for (int kc = 0; kc < 8; ++kc) {
            s16x8 b = *(const s16x8*)(bp + (8 + kc) * 512);
            acc[nt] = __builtin_amdgcn_mfma_f32_32x32x16_bf16(ahi[kc], b, acc[nt], 0, 0, 0);
        }
    }

    const int rbase = row0 + w * 32 + 4 * kg;
#pragma unroll
    for (int nt = 0; nt < 4; ++nt) {
        int col = nt * 32 + nin;
        float bv = bias[col];
#pragma unroll
        for (int reg = 0; reg < 16; ++reg) {
            int gr = rbase + (reg & 3) + 8 * (reg >> 2);
            float v = acc[nt][reg] + bv;
            if (RELU) v = fmaxf(v, 0.f);
            if (gr < NT) {
                C[(size_t)gr * 128 + col] = v;
                if (EMITB) CB[(size_t)gr * 128 + col] = f32_to_bf16(v);
            }
            acc[nt][reg] = (gr < NT) ? v : 0.f;
        }
    }

    if (STATS) {
        __syncthreads();
        float* ls = (float*)smem;
        ls[tid] = 0.f;
        __syncthreads();
#pragma unroll
        for (int nt = 0; nt < 4; ++nt) {
            int col = nt * 32 + nin;
            float s = 0.f, q = 0.f;
#pragma unroll
            for (int reg = 0; reg < 16; ++reg) { float v = acc[nt][reg]; s += v; q += v * v; }
            atomicAdd(&ls[col], s);
            atomicAdd(&ls[128 + col], q);
        }
        __syncthreads();
        if (tid < 128) {
            atomicAdd(&gsum[tid], ls[tid]);
            atomicAdd(&gsumsq[tid], ls[128 + tid]);
        }
    }
}

// ---------------------------------------------------------------------------
__global__ __launch_bounds__(128) void bnparam_kernel(const float* __restrict__ gsum,
                                                      const float* __restrict__ gsumsq,
                                                      const float* __restrict__ gamma,
                                                      const float* __restrict__ beta,
                                                      float* __restrict__ bn_a,
                                                      float* __restrict__ bn_b) {
    int c = threadIdx.x;
    float mu = gsum[c] * (1.0f / NT);
    float var = gsumsq[c] * (1.0f / NT) - mu * mu;
    float inv = rsqrtf(var + 1e-5f);
    float a = gamma[c] * inv;
    bn_a[c] = a;
    bn_b[c] = beta[c] - mu * a;
}

// ---------------------------------------------------------------------------
__global__ __launch_bounds__(256) void readout_kernel(const float* __restrict__ h,
                                                      const int* __restrict__ goff,
                                                      float* __restrict__ hg,
                                                      int colOff) {
    int g = blockIdx.x;
    int c = threadIdx.x & 127;
    int half = threadIdx.x >> 7;
    int beg = goff[g], end = goff[g + 1];
    float acc = 0.f;
    for (int n = beg + half; n < end; n += 2) acc += h[(size_t)n * 128 + c];
    __shared__ float ls[256];
    ls[threadIdx.x] = acc;
    __syncthreads();
    if (threadIdx.x < 128) hg[g * 256 + colOff + c] = ls[c] + ls[128 + c];
}

// ---------------------------------------------------------------------------
__global__ __launch_bounds__(128) void mlp_kernel(const float* __restrict__ hg,
                                                  const float* __restrict__ oW1,
                                                  const float* __restrict__ ob1,
                                                  const float* __restrict__ oW2,
                                                  const float* __restrict__ ob2,
                                                  const float* __restrict__ oW3,
                                                  const float* __restrict__ ob3,
                                                  float* __restrict__ out) {
    int g = blockIdx.x, t = threadIdx.x;
    __shared__ float sh[256];
    __shared__ float z[128];
    sh[t] = hg[g * 256 + t];
    sh[t + 128] = hg[g * 256 + 128 + t];
    __syncthreads();
    float acc = ob1[t];
    for (int k = 0; k < 256; ++k) acc = fmaf(sh[k], oW1[k * 128 + t], acc);
    float z1 = fmaxf(acc, 0.f);
    z[t] = z1;
    __syncthreads();
    acc = ob2[t];
    for (int k = 0; k < 128; ++k) acc = fmaf(z[k], oW2[k * 128 + t], acc);
    float z2 = fmaxf(acc, 0.f);
    float p = z2 * oW3[t];
    for (int off = 32; off > 0; off >>= 1) p += __shfl_down(p, off, 64);
    __shared__ float wsum[2];
    if ((t & 63) == 0) wsum[t >> 6] = p;
    __syncthreads();
    if (t == 0) out[g] = wsum[0] + wsum[1] + ob3[0];
}

// ---------------------------------------------------------------------------
extern "C" void kernel_launch(void* const* d_in, const int* in_sizes, int n_in,
                              void* d_out, int out_size, void* d_ws, size_t ws_size,
                              hipStream_t stream) {
    (void)in_sizes; (void)n_in; (void)out_size; (void)ws_size;
    const float* feats = (const float*)d_in[0];
    const int*   src   = (const int*)d_in[1];
    const int*   dst   = (const int*)d_in[2];
    const int*   gid   = (const int*)d_in[3];
    const float* epsp  = (const float*)d_in[5];
    const float* Wa    = (const float*)d_in[6];
    const float* ba    = (const float*)d_in[7];
    const float* bng   = (const float*)d_in[8];
    const float* bnb   = (const float*)d_in[9];
    const float* Wb    = (const float*)d_in[10];
    const float* bb    = (const float*)d_in[11];
    const float* oW1   = (const float*)d_in[12];
    const float* ob1   = (const float*)d_in[13];
    const float* oW2   = (const float*)d_in[14];
    const float* ob2   = (const float*)d_in[15];
    const float* oW3   = (const float*)d_in[16];
    const float* ob3   = (const float*)d_in[17];
    float* out = (float*)d_out;

    char* p = (char*)d_ws;
    auto carve = [&](size_t bytes) -> void* {
        void* r = (void*)p;
        p += (bytes + 255) & ~(size_t)255;
        return r;
    };
    unsigned short* Asplit = (unsigned short*)carve((size_t)NT * 256 * 2);
    float* bufY    = (float*)carve((size_t)NT * DIM * 4);
    float* bufH    = (float*)carve((size_t)NT * DIM * 4);
    unsigned short* featsB = (unsigned short*)carve((size_t)NT * DIM * 2);
    unsigned short* hB     = (unsigned short*)carve((size_t)NT * DIM * 2);
    unsigned short* Bfrag  = (unsigned short*)carve((size_t)8 * 32768 * 2);
    int*   esrc     = (int*)carve((size_t)NE * 4);
    unsigned int* partbuf = (unsigned int*)carve((size_t)NE * 4);
    int*   hcoarse  = (int*)carve((size_t)HCN * 4);
    int*   offbuf   = (int*)carve((size_t)HCN * 4);
    int*   bucketBase = (int*)carve((size_t)(NB + 1) * 4);
    int*   indptr   = (int*)carve((size_t)(NT + 1) * 4);
    int*   goff     = (int*)carve((size_t)(NG + 1) * 4);
    float* gsumAll  = (float*)carve((size_t)4 * 256 * 4);  // 4 layers x (sum|sumsq)
    float* bn_a     = (float*)carve(128 * 4);
    float* bn_b     = (float*)carve(128 * 4);
    float* hg       = (float*)carve((size_t)NG * 256 * 4);

    const int CB = (NT * 32 + 255) / 256;   // tobf16 blocks

    ranges_kernel<<<1, 256, 0, stream>>>(gid, goff);
    bsplit_kernel<<<64, 256, 0, stream>>>(Wa, Wb, Bfrag);
    tobf16_kernel<<<CB, 256, 0, stream>>>(feats, featsB);
    hipMemsetAsync(gsumAll, 0, (size_t)4 * 256 * 4, stream);

    for (int e = 0; e < 2; ++e) {
        // CSR by dst: 2-level counting sort, LDS atomics only
        csr_part_hist_kernel<<<PB, 256, 0, stream>>>(dst + e * NE, hcoarse);
        csr_scan_kernel<<<1, 1024, 0, stream>>>(hcoarse, offbuf, bucketBase, indptr);
        csr_scatter_kernel<<<PB, 256, 0, stream>>>(src + e * NE, dst + e * NE,
                                                   offbuf, partbuf);
        csr_finalize_kernel<<<NB, 256, 0, stream>>>(partbuf, bucketBase,
                                                    indptr, esrc);
        for (int l = 0; l < 2; ++l) {
            int wi = e * 2 + l;
            float* gsum = gsumAll + wi * 256;
            float* gsumsq = gsum + 128;
            if (l == 0)
                agg_split_kernel<<<(NT + 7) / 8, 256, 0, stream>>>(
                    feats, featsB, indptr, esrc, epsp, wi, Asplit);
            else
                agg_split_kernel<<<(NT + 7) / 8, 256, 0, stream>>>(
                    bufH, hB, indptr, esrc, epsp, wi, Asplit);
            mfma_gemm_kernel<0, 1, 0, 0><<<GEMM_B, 256, 0, stream>>>(
                Asplit, Bfrag + (size_t)wi * 32768, ba + (size_t)wi * DIM,
                nullptr, nullptr, bufY, nullptr, gsum, gsumsq);
            bnparam_kernel<<<1, 128, 0, stream>>>(gsum, gsumsq,
                                                  bng + (size_t)wi * DIM,
                                                  bnb + (size_t)wi * DIM,
                                                  bn_a, bn_b);
            if (l == 0)
                mfma_gemm_kernel<1, 0, 1, 1><<<GEMM_B, 256, 0, stream>>>(
                    bufY, Bfrag + (size_t)(4 + wi) * 32768, bb + (size_t)wi * DIM,
                    bn_a, bn_b, bufH, hB, nullptr, nullptr);
            else
                mfma_gemm_kernel<1, 0, 0, 0><<<GEMM_B, 256, 0, stream>>>(
                    bufY, Bfrag + (size_t)(4 + wi) * 32768, bb + (size_t)wi * DIM,
                    bn_a, bn_b, bufH, nullptr, nullptr, nullptr);
        }
        readout_kernel<<<NG, 256, 0, stream>>>(bufH, goff, hg, e * 128);
    }
    mlp_kernel<<<NG, 128, 0, stream>>>(hg, oW1, ob1, oW2, ob2, oW3, ob3, out);
}

// Round 7
// 642.202 us; speedup vs baseline: 1.8131x; 1.0425x over previous
//
#include <hip/hip_runtime.h>

#define NT 50000   // nodes
#define NE 800000  // edges per edge-type
#define NG 256     // graphs
#define DIM 128
#define GEMM_B ((NT + 127) / 128)    // 391 MFMA-GEMM blocks

// CSR-build partition constants
#define NB 128                        // coarse dst buckets
#define BW 391                        // bucket width: 128*391 = 50048 >= NT
#define PB 196                        // partition blocks
#define PCH 4096                      // edges per partition block
#define HCN (NB * PB)                 // 25088

typedef short s16x8 __attribute__((ext_vector_type(8)));
typedef float f32x16 __attribute__((ext_vector_type(16)));

__device__ __forceinline__ unsigned short f32_to_bf16(float f) {
    unsigned int u = __float_as_uint(f);
    u += 0x7FFFu + ((u >> 16) & 1u);   // round-to-nearest-even
    return (unsigned short)(u >> 16);
}
__device__ __forceinline__ float bf16_to_f32(unsigned short h) {
    return __uint_as_float(((unsigned int)h) << 16);
}

// ---------------------------------------------------------------------------
__global__ __launch_bounds__(256) void ranges_kernel(const int* __restrict__ gid,
                                                     int* __restrict__ goff) {
    int g = threadIdx.x;
    int lo = 0, hi = NT;
    while (lo < hi) {
        int mid = (lo + hi) >> 1;
        if (gid[mid] < g) lo = mid + 1; else hi = mid;
    }
    goff[g] = lo;
    if (g == 0) goff[NG] = NT;
}

// ---------------------------------------------------------------------------
__global__ __launch_bounds__(256) void tobf16_kernel(const float* __restrict__ in,
                                                     unsigned short* __restrict__ out) {
    int i = blockIdx.x * 256 + threadIdx.x;
    if (i >= NT * 32) return;
    float4 v = ((const float4*)in)[i];
    ushort4 o;
    o.x = f32_to_bf16(v.x); o.y = f32_to_bf16(v.y);
    o.z = f32_to_bf16(v.z); o.w = f32_to_bf16(v.w);
    ((ushort4*)out)[i] = o;
}

// ---------------------------------------------------------------------------
// CSR build (both edge types at once, blockIdx.y = e), 2-level counting sort
// ---------------------------------------------------------------------------
__global__ __launch_bounds__(256) void csr_part_hist_kernel(
        const int* __restrict__ dstAll, int* __restrict__ hcoarseAll) {
    const int* dst = dstAll + (size_t)blockIdx.y * NE;
    int* hcoarse = hcoarseAll + (size_t)blockIdx.y * HCN;
    __shared__ int h[NB];
    if (threadIdx.x < NB) h[threadIdx.x] = 0;
    __syncthreads();
#pragma unroll
    for (int i = 0; i < PCH / 256; ++i) {
        int e = blockIdx.x * PCH + i * 256 + threadIdx.x;
        if (e < NE) atomicAdd(&h[dst[e] / BW], 1);
    }
    __syncthreads();
    if (threadIdx.x < NB)
        hcoarse[threadIdx.x * PB + blockIdx.x] = h[threadIdx.x];
}

__global__ __launch_bounds__(1024) void csr_scan_kernel(
        const int* __restrict__ hcoarseAll, int* __restrict__ offAll,
        int* __restrict__ bucketBaseAll, int* __restrict__ indptrAll) {
    const int* hcoarse = hcoarseAll + (size_t)blockIdx.x * HCN;
    int* off = offAll + (size_t)blockIdx.x * HCN;
    int* bucketBase = bucketBaseAll + (size_t)blockIdx.x * (NB + 1);
    int* indptr = indptrAll + (size_t)blockIdx.x * (NT + 1);
    __shared__ int ps[1024];
    int t = threadIdx.x;
    const int CH = (HCN + 1023) / 1024;  // 25
    int beg = t * CH, end = beg + CH; if (end > HCN) end = HCN;
    int s = 0;
    for (int i = beg; i < end; ++i) s += hcoarse[i];
    ps[t] = s;
    __syncthreads();
    for (int o = 1; o < 1024; o <<= 1) {
        int v = (t >= o) ? ps[t - o] : 0;
        __syncthreads();
        ps[t] += v;
        __syncthreads();
    }
    int run = (t == 0) ? 0 : ps[t - 1];
    for (int i = beg; i < end; ++i) {
        off[i] = run;
        if (i % PB == 0) bucketBase[i / PB] = run;
        run += hcoarse[i];
    }
    if (t == 1023) bucketBase[NB] = NE;
    if (t == 0) indptr[NT] = NE;
}

__global__ __launch_bounds__(256) void csr_scatter_kernel(
        const int* __restrict__ srcAll, const int* __restrict__ dstAll,
        const int* __restrict__ offAll, unsigned int* __restrict__ partAll) {
    const int* src = srcAll + (size_t)blockIdx.y * NE;
    const int* dst = dstAll + (size_t)blockIdx.y * NE;
    const int* off = offAll + (size_t)blockIdx.y * HCN;
    unsigned int* part = partAll + (size_t)blockIdx.y * NE;
    __shared__ int cur[NB];
    if (threadIdx.x < NB) cur[threadIdx.x] = off[threadIdx.x * PB + blockIdx.x];
    __syncthreads();
#pragma unroll
    for (int i = 0; i < PCH / 256; ++i) {
        int e = blockIdx.x * PCH + i * 256 + threadIdx.x;
        if (e < NE) {
            int d = dst[e];
            int b = d / BW;
            int pos = atomicAdd(&cur[b], 1);
            part[pos] = ((unsigned int)(d - b * BW) << 16) | (unsigned int)src[e];
        }
    }
}

__global__ __launch_bounds__(256) void csr_finalize_kernel(
        const unsigned int* __restrict__ partAll,
        const int* __restrict__ bucketBaseAll,
        int* __restrict__ indptrAll, int* __restrict__ esrcAll) {
    const unsigned int* part = partAll + (size_t)blockIdx.y * NE;
    const int* bucketBase = bucketBaseAll + (size_t)blockIdx.y * (NB + 1);
    int* indptr = indptrAll + (size_t)blockIdx.y * (NT + 1);
    int* esrc = esrcAll + (size_t)blockIdx.y * NE;
    __shared__ int cnt[512];
    __shared__ int excl[512];
    __shared__ int ps[256];
    __shared__ int cur[BW + 1];
    int b = blockIdx.x, t = threadIdx.x;
    int base = bucketBase[b];
    int n = bucketBase[b + 1] - base;
    cnt[t] = 0; cnt[t + 256] = 0;
    for (int j = t; j <= BW; j += 256) cur[j] = 0;
    __syncthreads();
    for (int i = t; i < n; i += 256) atomicAdd(&cnt[part[base + i] >> 16], 1);
    __syncthreads();
    int a0 = cnt[2 * t], a1 = cnt[2 * t + 1];
    ps[t] = a0 + a1;
    __syncthreads();
    for (int o = 1; o < 256; o <<= 1) {
        int v = (t >= o) ? ps[t - o] : 0;
        __syncthreads();
        ps[t] += v;
        __syncthreads();
    }
    int before = (t == 0) ? 0 : ps[t - 1];
    excl[2 * t] = before;
    excl[2 * t + 1] = before + a0;
    __syncthreads();
    int node0 = b * BW;
    for (int j = t; j < BW; j += 256) {
        int gn = node0 + j;
        if (gn < NT) indptr[gn] = base + excl[j];
    }
    for (int i = t; i < n; i += 256) {
        unsigned int pk = part[base + i];
        int dl = pk >> 16;
        int pos = atomicAdd(&cur[dl], 1);
        esrc[base + excl[dl] + pos] = (int)(pk & 0xFFFFu);
    }
}

// ---------------------------------------------------------------------------
// Weight split + frag-major repack (see R4 comment).
// ---------------------------------------------------------------------------
__global__ __launch_bounds__(256) void bsplit_kernel(const float* __restrict__ Wa,
                                                     const float* __restrict__ Wb,
                                                     unsigned short* __restrict__ Bfrag) {
    int slot = blockIdx.x >> 3;
    int sub = blockIdx.x & 7;
    const float* W = (slot < 4) ? (Wa + (size_t)slot * DIM * DIM)
                                : (Wb + (size_t)(slot - 4) * DIM * DIM);
    unsigned short* out = Bfrag + (size_t)slot * 32768;
    for (int i = 0; i < 16; ++i) {
        int e = sub * 4096 + i * 256 + threadIdx.x;
        int kphys = e >> 7, n = e & 127;
        int k = kphys & 127;
        float wv = W[k * 128 + n];
        unsigned short hi = f32_to_bf16(wv);
        unsigned short val = (kphys < 128) ? hi : f32_to_bf16(wv - bf16_to_f32(hi));
        int nt = n >> 5, nin = n & 31;
        int kcp = kphys >> 4, kgp = (kphys >> 3) & 1, jj = kphys & 7;
        out[(size_t)(((nt * 16 + kcp) * 64) + kgp * 32 + nin) * 8 + jj] = val;
    }
}

// ---------------------------------------------------------------------------
// Fused GEMM. GATHER: A = (1+eps)*Afp32[row] + sum hb[esrc[...]] (in-register
// aggregation, hi/lo split). !GATHER: A = relu(bn(Afp32[row])) w/ BN params
// computed per-block from gsumIn (BNCALC). STATS: column sum/sumsq of output.
// EMITB: also write bf16 mirror of C. Tile 128x128, 4 waves, B' in 64KB LDS.
// ---------------------------------------------------------------------------
template <int GATHER, int STATS, int RELU, int EMITB, int BNCALC>
__global__ __launch_bounds__(256) void fused_gemm_kernel(
        const float* __restrict__ Afp32,
        const unsigned short* __restrict__ hb,
        const int* __restrict__ indptr, const int* __restrict__ esrc,
        const float* __restrict__ eps_p, int eps_idx,
        const unsigned short* __restrict__ Bfrag,
        const float* __restrict__ bias,
        const float* __restrict__ gsumIn, const float* __restrict__ gamma,
        const float* __restrict__ beta,
        float* __restrict__ C, unsigned short* __restrict__ CBout,
        float* __restrict__ gsum, float* __restrict__ gsumsq) {
    __shared__ char smem[65536 + 1024];
    unsigned short* sB = (unsigned short*)smem;
    float* sBNa = (float*)(smem + 65536);
    float* sBNb = sBNa + 128;
    const int tid = threadIdx.x;
    const int w = tid >> 6, lane = tid & 63;
    const int nin = lane & 31, kg = lane >> 5;
    const int row0 = blockIdx.x * 128;
    const int myrow = row0 + w * 32 + nin;
    const int rowc = myrow < NT ? myrow : NT - 1;

    // stage whole B' into LDS
    {
        const uint4* Bg = (const uint4*)Bfrag;
        uint4* sB4 = (uint4*)smem;
#pragma unroll
        for (int i = 0; i < 16; ++i) sB4[tid + 256 * i] = Bg[tid + 256 * i];
    }
    if (BNCALC && tid < 128) {
        float mu = gsumIn[tid] * (1.0f / NT);
        float var = gsumIn[128 + tid] * (1.0f / NT) - mu * mu;
        float inv = rsqrtf(var + 1e-5f);
        float a = gamma[tid] * inv;
        sBNa[tid] = a;
        sBNb[tid] = beta[tid] - mu * a;
    }

    s16x8 ahi[8], alo[8];
    if (GATHER) {
        // in-register aggregation: lane owns 64 cols (kc*16+kg*8 .. +7)
        float av[8][8];
        float e1 = 1.0f + eps_p[eps_idx];
        const float* hr = Afp32 + (size_t)rowc * 128 + kg * 8;
#pragma unroll
        for (int kc = 0; kc < 8; ++kc) {
            float4 y0 = *(const float4*)(hr + kc * 16);
            float4 y1 = *(const float4*)(hr + kc * 16 + 4);
            av[kc][0] = e1 * y0.x; av[kc][1] = e1 * y0.y;
            av[kc][2] = e1 * y0.z; av[kc][3] = e1 * y0.w;
            av[kc][4] = e1 * y1.x; av[kc][5] = e1 * y1.y;
            av[kc][6] = e1 * y1.z; av[kc][7] = e1 * y1.w;
        }
        int beg = indptr[rowc], end = indptr[rowc + 1];
        int j = beg;
        for (; j + 2 <= end; j += 2) {
            int s0 = esrc[j], s1 = esrc[j + 1];
            const unsigned short* n0 = hb + (size_t)s0 * 128 + kg * 8;
            const unsigned short* n1 = hb + (size_t)s1 * 128 + kg * 8;
#pragma unroll
            for (int kc = 0; kc < 8; ++kc) {
                union { s16x8 v; unsigned short u[8]; } U0, U1;
                U0.v = *(const s16x8*)(n0 + kc * 16);
                U1.v = *(const s16x8*)(n1 + kc * 16);
#pragma unroll
                for (int q = 0; q < 8; ++q)
                    av[kc][q] += bf16_to_f32(U0.u[q]) + bf16_to_f32(U1.u[q]);
            }
        }
        if (j < end) {
            const unsigned short* n0 = hb + (size_t)esrc[j] * 128 + kg * 8;
#pragma unroll
            for (int kc = 0; kc < 8; ++kc) {
                union { s16x8 v; unsigned short u[8]; } U0;
                U0.v = *(const s16x8*)(n0 + kc * 16);
#pragma unroll
                for (int q = 0; q < 8; ++q) av[kc][q] += bf16_to_f32(U0.u[q]);
            }
        }
#pragma unroll
        for (int kc = 0; kc < 8; ++kc) {
            union { s16x8 v; unsigned short u[8]; } H, L;
#pragma unroll
            for (int q = 0; q < 8; ++q) {
                H.u[q] = f32_to_bf16(av[kc][q]);
                L.u[q] = f32_to_bf16(av[kc][q] - bf16_to_f32(H.u[q]));
            }
            ahi[kc] = H.v; alo[kc] = L.v;
        }
        __syncthreads();
    } else {
        __syncthreads();   // sBN ready (and B, before first use below)
        const float* yr = Afp32 + (size_t)rowc * 128 + kg * 8;
#pragma unroll
        for (int kc = 0; kc < 8; ++kc) {
            int c0 = kc * 16 + kg * 8;
            float4 y0 = *(const float4*)(yr + kc * 16);
            float4 y1 = *(const float4*)(yr + kc * 16 + 4);
            float4 a0 = *(const float4*)(sBNa + c0);
            float4 a1 = *(const float4*)(sBNa + c0 + 4);
            float4 b0 = *(const float4*)(sBNb + c0);
            float4 b1 = *(const float4*)(sBNb + c0 + 4);
            float t[8];
            t[0] = fmaxf(0.f, fmaf(y0.x, a0.x, b0.x));
            t[1] = fmaxf(0.f, fmaf(y0.y, a0.y, b0.y));
            t[2] = fmaxf(0.f, fmaf(y0.z, a0.z, b0.z));
            t[3] = fmaxf(0.f, fmaf(y0.w, a0.w, b0.w));
            t[4] = fmaxf(0.f, fmaf(y1.x, a1.x, b1.x));
            t[5] = fmaxf(0.f, fmaf(y1.y, a1.y, b1.y));
            t[6] = fmaxf(0.f, fmaf(y1.z, a1.z, b1.z));
            t[7] = fmaxf(0.f, fmaf(y1.w, a1.w, b1.w));
            union { s16x8 v; unsigned short u[8]; } H, L;
#pragma unroll
            for (int q = 0; q < 8; ++q) {
                H.u[q] = f32_to_bf16(t[q]);
                L.u[q] = f32_to_bf16(t[q] - bf16_to_f32(H.u[q]));
            }
            ahi[kc] = H.v; alo[kc] = L.v;
        }
    }

    f32x16 acc[4];
#pragma unroll
    for (int nt = 0; nt < 4; ++nt)
#pragma unroll
        for (int r = 0; r < 16; ++r) acc[nt][r] = 0.f;

#pragma unroll
    for (int nt = 0; nt < 4; ++nt) {
        const unsigned short* bp = sB + (size_t)(nt * 16) * 512 + lane * 8;
#pragma unroll
        for (int kc = 0; kc < 8; ++kc) {
            s16x8 b = *(const s16x8*)(bp + kc * 512);
            acc[nt] = __builtin_amdgcn_mfma_f32_32x32x16_bf16(ahi[kc], b, acc[nt], 0, 0, 0);
            acc[nt] = __builtin_amdgcn_mfma_f32_32x32x16_bf16(alo[kc], b, acc[nt], 0, 0, 0);
        }
#pragma unroll
        for (int kc = 0; kc < 8; ++kc) {
            s16x8 b = *(const s16x8*)(bp + (8 + kc) * 512);
            acc[nt] = __builtin_amdgcn_mfma_f32_32x32x16_bf16(ahi[kc], b, acc[nt], 0, 0, 0);
        }
    }

    const int rbase = row0 + w * 32 + 4 * kg;
#pragma unroll
    for (int nt = 0; nt < 4; ++nt) {
        int col = nt * 32 + nin;
        float bv = bias[col];
#pragma unroll
        for (int reg = 0; reg < 16; ++reg) {
            int gr = rbase + (reg & 3) + 8 * (reg >> 2);
            float v = acc[nt][reg] + bv;
            if (RELU) v = fmaxf(v, 0.f);
            if (gr < NT) {
                C[(size_t)gr * 128 + col] = v;
                if (EMITB) CBout[(size_t)gr * 128 + col] = f32_to_bf16(v);
            }
            acc[nt][reg] = (gr < NT) ? v : 0.f;
        }
    }

    if (STATS) {
        __syncthreads();
        float* ls = (float*)smem;
        ls[tid] = 0.f;
        __syncthreads();
#pragma unroll
        for (int nt = 0; nt < 4; ++nt) {
            int col = nt * 32 + nin;
            float s = 0.f, q = 0.f;
#pragma unroll
            for (int reg = 0; reg < 16; ++reg) { float v = acc[nt][reg]; s += v; q += v * v; }
            atomicAdd(&ls[col], s);
            atomicAdd(&ls[128 + col], q);
        }
        __syncthreads();
        if (tid < 128) {
            atomicAdd(&gsum[tid], ls[tid]);
            atomicAdd(&gsumsq[tid], ls[128 + tid]);
        }
    }
}

// ---------------------------------------------------------------------------
// Readout: 2 blocks per graph, 4-deep unrolled row accumulation, partials.
// ---------------------------------------------------------------------------
__global__ __launch_bounds__(256) void readout_kernel(const float* __restrict__ h,
                                                      const int* __restrict__ goff,
                                                      float* __restrict__ hgp,
                                                      int colOff) {
    int g = blockIdx.x >> 1, h2 = blockIdx.x & 1;
    int c = threadIdx.x & 127, rr = threadIdx.x >> 7;
    int beg = goff[g], end = goff[g + 1];
    int n = beg + h2 * 2 + rr;   // stride 4 across the block pair
    float a0 = 0.f, a1 = 0.f, a2 = 0.f, a3 = 0.f;
    for (; n + 12 < end; n += 16) {
        a0 += h[(size_t)n * 128 + c];
        a1 += h[(size_t)(n + 4) * 128 + c];
        a2 += h[(size_t)(n + 8) * 128 + c];
        a3 += h[(size_t)(n + 12) * 128 + c];
    }
    for (; n < end; n += 4) a0 += h[(size_t)n * 128 + c];
    float acc = (a0 + a1) + (a2 + a3);
    __shared__ float ls[256];
    ls[threadIdx.x] = acc;
    __syncthreads();
    if (threadIdx.x < 128)
        hgp[(size_t)h2 * NG * 256 + g * 256 + colOff + c] = ls[c] + ls[128 + c];
}

// ---------------------------------------------------------------------------
__global__ __launch_bounds__(128) void mlp_kernel(const float* __restrict__ hgp,
                                                  const float* __restrict__ oW1,
                                                  const float* __restrict__ ob1,
                                                  const float* __restrict__ oW2,
                                                  const float* __restrict__ ob2,
                                                  const float* __restrict__ oW3,
                                                  const float* __restrict__ ob3,
                                                  float* __restrict__ out) {
    int g = blockIdx.x, t = threadIdx.x;
    __shared__ float sh[256];
    __shared__ float z[128];
    sh[t] = hgp[g * 256 + t] + hgp[(size_t)NG * 256 + g * 256 + t];
    sh[t + 128] = hgp[g * 256 + 128 + t] + hgp[(size_t)NG * 256 + g * 256 + 128 + t];
    __syncthreads();
    float acc = ob1[t];
    for (int k = 0; k < 256; ++k) acc = fmaf(sh[k], oW1[k * 128 + t], acc);
    float z1 = fmaxf(acc, 0.f);
    z[t] = z1;
    __syncthreads();
    acc = ob2[t];
    for (int k = 0; k < 128; ++k) acc = fmaf(z[k], oW2[k * 128 + t], acc);
    float z2 = fmaxf(acc, 0.f);
    float p = z2 * oW3[t];
    for (int off = 32; off > 0; off >>= 1) p += __shfl_down(p, off, 64);
    __shared__ float wsum[2];
    if ((t & 63) == 0) wsum[t >> 6] = p;
    __syncthreads();
    if (t == 0) out[g] = wsum[0] + wsum[1] + ob3[0];
}

// ---------------------------------------------------------------------------
extern "C" void kernel_launch(void* const* d_in, const int* in_sizes, int n_in,
                              void* d_out, int out_size, void* d_ws, size_t ws_size,
                              hipStream_t stream) {
    (void)in_sizes; (void)n_in; (void)out_size; (void)ws_size;
    const float* feats = (const float*)d_in[0];
    const int*   src   = (const int*)d_in[1];
    const int*   dst   = (const int*)d_in[2];
    const int*   gid   = (const int*)d_in[3];
    const float* epsp  = (const float*)d_in[5];
    const float* Wa    = (const float*)d_in[6];
    const float* ba    = (const float*)d_in[7];
    const float* bng   = (const float*)d_in[8];
    const float* bnb   = (const float*)d_in[9];
    const float* Wb    = (const float*)d_in[10];
    const float* bb    = (const float*)d_in[11];
    const float* oW1   = (const float*)d_in[12];
    const float* ob1   = (const float*)d_in[13];
    const float* oW2   = (const float*)d_in[14];
    const float* ob2   = (const float*)d_in[15];
    const float* oW3   = (const float*)d_in[16];
    const float* ob3   = (const float*)d_in[17];
    float* out = (float*)d_out;

    char* p = (char*)d_ws;
    auto carve = [&](size_t bytes) -> void* {
        void* r = (void*)p;
        p += (bytes + 255) & ~(size_t)255;
        return r;
    };
    float* bufY    = (float*)carve((size_t)NT * DIM * 4);
    float* bufH    = (float*)carve((size_t)NT * DIM * 4);
    unsigned short* featsB = (unsigned short*)carve((size_t)NT * DIM * 2);
    unsigned short* hB     = (unsigned short*)carve((size_t)NT * DIM * 2);
    unsigned short* Bfrag  = (unsigned short*)carve((size_t)8 * 32768 * 2);
    int*   esrc2    = (int*)carve((size_t)2 * NE * 4);
    unsigned int* part2 = (unsigned int*)carve((size_t)2 * NE * 4);
    int*   hcoarse2 = (int*)carve((size_t)2 * HCN * 4);
    int*   offbuf2  = (int*)carve((size_t)2 * HCN * 4);
    int*   bb2      = (int*)carve((size_t)2 * (NB + 1) * 4);
    int*   indptr2  = (int*)carve((size_t)2 * (NT + 1) * 4);
    int*   goff     = (int*)carve((size_t)(NG + 1) * 4);
    float* gsumAll  = (float*)carve((size_t)4 * 256 * 4);  // 4 layers x (sum|sumsq)
    float* hgp      = (float*)carve((size_t)2 * NG * 256 * 4);

    const int CB = (NT * 32 + 255) / 256;

    ranges_kernel<<<1, 256, 0, stream>>>(gid, goff);
    bsplit_kernel<<<64, 256, 0, stream>>>(Wa, Wb, Bfrag);
    tobf16_kernel<<<CB, 256, 0, stream>>>(feats, featsB);
    hipMemsetAsync(gsumAll, 0, (size_t)4 * 256 * 4, stream);

    // CSR for both edge types, up front
    csr_part_hist_kernel<<<dim3(PB, 2), 256, 0, stream>>>(dst, hcoarse2);
    csr_scan_kernel<<<2, 1024, 0, stream>>>(hcoarse2, offbuf2, bb2, indptr2);
    csr_scatter_kernel<<<dim3(PB, 2), 256, 0, stream>>>(src, dst, offbuf2, part2);
    csr_finalize_kernel<<<dim3(NB, 2), 256, 0, stream>>>(part2, bb2, indptr2, esrc2);

    for (int e = 0; e < 2; ++e) {
        const int* indptr = indptr2 + (size_t)e * (NT + 1);
        const int* esrc   = esrc2 + (size_t)e * NE;
        for (int l = 0; l < 2; ++l) {
            int wi = e * 2 + l;
            float* gsum = gsumAll + wi * 256;
            float* gsumsq = gsum + 128;
            const float* hSrc = (l == 0) ? feats : bufH;
            const unsigned short* hbSrc = (l == 0) ? featsB : hB;
            // GEMM1 with fused aggregation + stats
            fused_gemm_kernel<1, 1, 0, 0, 0><<<GEMM_B, 256, 0, stream>>>(
                hSrc, hbSrc, indptr, esrc, epsp, wi,
                Bfrag + (size_t)wi * 32768, ba + (size_t)wi * DIM,
                nullptr, nullptr, nullptr, bufY, nullptr, gsum, gsumsq);
            // GEMM2 with fused BN-param calc (+relu/bf16-mirror on l==0)
            if (l == 0)
                fused_gemm_kernel<0, 0, 1, 1, 1><<<GEMM_B, 256, 0, stream>>>(
                    bufY, nullptr, nullptr, nullptr, nullptr, 0,
                    Bfrag + (size_t)(4 + wi) * 32768, bb + (size_t)wi * DIM,
                    gsum, bng + (size_t)wi * DIM, bnb + (size_t)wi * DIM,
                    bufH, hB, nullptr, nullptr);
            else
                fused_gemm_kernel<0, 0, 0, 0, 1><<<GEMM_B, 256, 0, stream>>>(
                    bufY, nullptr, nullptr, nullptr, nullptr, 0,
                    Bfrag + (size_t)(4 + wi) * 32768, bb + (size_t)wi * DIM,
                    gsum, bng + (size_t)wi * DIM, bnb + (size_t)wi * DIM,
                    bufH, nullptr, nullptr, nullptr);
        }
        readout_kernel<<<NG * 2, 256, 0, stream>>>(bufH, goff, hgp, e * 128);
    }
    mlp_kernel<<<NG, 128, 0, stream>>>(hgp, oW1, ob1, oW2, ob2, oW3, ob3, out);
}

// Round 8
// 550.726 us; speedup vs baseline: 2.1143x; 1.1661x over previous
//
#include <hip/hip_runtime.h>

#define NT 50000   // nodes
#define NE 800000  // edges per edge-type
#define NG 256     // graphs
#define DIM 128
#define GEMM_B ((NT + 127) / 128)    // 391 MFMA-GEMM blocks

// CSR-build partition constants
#define NB 128                        // coarse dst buckets
#define BW 391                        // bucket width: 128*391 = 50048 >= NT
#define PB 196                        // partition blocks
#define PCH 4096                      // edges per partition block
#define HCN (NB * PB)                 // 25088

typedef short s16x8 __attribute__((ext_vector_type(8)));
typedef float f32x16 __attribute__((ext_vector_type(16)));

__device__ __forceinline__ unsigned short f32_to_bf16(float f) {
    unsigned int u = __float_as_uint(f);
    u += 0x7FFFu + ((u >> 16) & 1u);   // round-to-nearest-even
    return (unsigned short)(u >> 16);
}
__device__ __forceinline__ float bf16_to_f32(unsigned short h) {
    return __uint_as_float(((unsigned int)h) << 16);
}

// ---------------------------------------------------------------------------
__global__ __launch_bounds__(256) void ranges_kernel(const int* __restrict__ gid,
                                                     int* __restrict__ goff) {
    int g = threadIdx.x;
    int lo = 0, hi = NT;
    while (lo < hi) {
        int mid = (lo + hi) >> 1;
        if (gid[mid] < g) lo = mid + 1; else hi = mid;
    }
    goff[g] = lo;
    if (g == 0) goff[NG] = NT;
}

// ---------------------------------------------------------------------------
__global__ __launch_bounds__(256) void tobf16_kernel(const float* __restrict__ in,
                                                     unsigned short* __restrict__ out) {
    int i = blockIdx.x * 256 + threadIdx.x;
    if (i >= NT * 32) return;
    float4 v = ((const float4*)in)[i];
    ushort4 o;
    o.x = f32_to_bf16(v.x); o.y = f32_to_bf16(v.y);
    o.z = f32_to_bf16(v.z); o.w = f32_to_bf16(v.w);
    ((ushort4*)out)[i] = o;
}

// ---------------------------------------------------------------------------
// CSR build (both edge types at once, blockIdx.y = e), 2-level counting sort
// ---------------------------------------------------------------------------
__global__ __launch_bounds__(256) void csr_part_hist_kernel(
        const int* __restrict__ dstAll, int* __restrict__ hcoarseAll) {
    const int* dst = dstAll + (size_t)blockIdx.y * NE;
    int* hcoarse = hcoarseAll + (size_t)blockIdx.y * HCN;
    __shared__ int h[NB];
    if (threadIdx.x < NB) h[threadIdx.x] = 0;
    __syncthreads();
#pragma unroll
    for (int i = 0; i < PCH / 256; ++i) {
        int e = blockIdx.x * PCH + i * 256 + threadIdx.x;
        if (e < NE) atomicAdd(&h[dst[e] / BW], 1);
    }
    __syncthreads();
    if (threadIdx.x < NB)
        hcoarse[threadIdx.x * PB + blockIdx.x] = h[threadIdx.x];
}

__global__ __launch_bounds__(1024) void csr_scan_kernel(
        const int* __restrict__ hcoarseAll, int* __restrict__ offAll,
        int* __restrict__ bucketBaseAll, int* __restrict__ indptrAll) {
    const int* hcoarse = hcoarseAll + (size_t)blockIdx.x * HCN;
    int* off = offAll + (size_t)blockIdx.x * HCN;
    int* bucketBase = bucketBaseAll + (size_t)blockIdx.x * (NB + 1);
    int* indptr = indptrAll + (size_t)blockIdx.x * (NT + 1);
    __shared__ int ps[1024];
    int t = threadIdx.x;
    const int CH = (HCN + 1023) / 1024;  // 25
    int beg = t * CH, end = beg + CH; if (end > HCN) end = HCN;
    int s = 0;
    for (int i = beg; i < end; ++i) s += hcoarse[i];
    ps[t] = s;
    __syncthreads();
    for (int o = 1; o < 1024; o <<= 1) {
        int v = (t >= o) ? ps[t - o] : 0;
        __syncthreads();
        ps[t] += v;
        __syncthreads();
    }
    int run = (t == 0) ? 0 : ps[t - 1];
    for (int i = beg; i < end; ++i) {
        off[i] = run;
        if (i % PB == 0) bucketBase[i / PB] = run;
        run += hcoarse[i];
    }
    if (t == 1023) bucketBase[NB] = NE;
    if (t == 0) indptr[NT] = NE;
}

__global__ __launch_bounds__(256) void csr_scatter_kernel(
        const int* __restrict__ srcAll, const int* __restrict__ dstAll,
        const int* __restrict__ offAll, unsigned int* __restrict__ partAll) {
    const int* src = srcAll + (size_t)blockIdx.y * NE;
    const int* dst = dstAll + (size_t)blockIdx.y * NE;
    const int* off = offAll + (size_t)blockIdx.y * HCN;
    unsigned int* part = partAll + (size_t)blockIdx.y * NE;
    __shared__ int cur[NB];
    if (threadIdx.x < NB) cur[threadIdx.x] = off[threadIdx.x * PB + blockIdx.x];
    __syncthreads();
#pragma unroll
    for (int i = 0; i < PCH / 256; ++i) {
        int e = blockIdx.x * PCH + i * 256 + threadIdx.x;
        if (e < NE) {
            int d = dst[e];
            int b = d / BW;
            int pos = atomicAdd(&cur[b], 1);
            part[pos] = ((unsigned int)(d - b * BW) << 16) | (unsigned int)src[e];
        }
    }
}

__global__ __launch_bounds__(256) void csr_finalize_kernel(
        const unsigned int* __restrict__ partAll,
        const int* __restrict__ bucketBaseAll,
        int* __restrict__ indptrAll, int* __restrict__ esrcAll) {
    const unsigned int* part = partAll + (size_t)blockIdx.y * NE;
    const int* bucketBase = bucketBaseAll + (size_t)blockIdx.y * (NB + 1);
    int* indptr = indptrAll + (size_t)blockIdx.y * (NT + 1);
    int* esrc = esrcAll + (size_t)blockIdx.y * NE;
    __shared__ int cnt[512];
    __shared__ int excl[512];
    __shared__ int ps[256];
    __shared__ int cur[BW + 1];
    int b = blockIdx.x, t = threadIdx.x;
    int base = bucketBase[b];
    int n = bucketBase[b + 1] - base;
    cnt[t] = 0; cnt[t + 256] = 0;
    for (int j = t; j <= BW; j += 256) cur[j] = 0;
    __syncthreads();
    for (int i = t; i < n; i += 256) atomicAdd(&cnt[part[base + i] >> 16], 1);
    __syncthreads();
    int a0 = cnt[2 * t], a1 = cnt[2 * t + 1];
    ps[t] = a0 + a1;
    __syncthreads();
    for (int o = 1; o < 256; o <<= 1) {
        int v = (t >= o) ? ps[t - o] : 0;
        __syncthreads();
        ps[t] += v;
        __syncthreads();
    }
    int before = (t == 0) ? 0 : ps[t - 1];
    excl[2 * t] = before;
    excl[2 * t + 1] = before + a0;
    __syncthreads();
    int node0 = b * BW;
    for (int j = t; j < BW; j += 256) {
        int gn = node0 + j;
        if (gn < NT) indptr[gn] = base + excl[j];
    }
    for (int i = t; i < n; i += 256) {
        unsigned int pk = part[base + i];
        int dl = pk >> 16;
        int pos = atomicAdd(&cur[dl], 1);
        esrc[base + excl[dl] + pos] = (int)(pk & 0xFFFFu);
    }
}

// ---------------------------------------------------------------------------
// Aggregation + bf16 hi/lo split (standalone: 32 lanes/node = full edge burst
// parallelism; 8-deep unroll = 8 outstanding loads/lane to hide L2/HBM latency)
// ---------------------------------------------------------------------------
__global__ __launch_bounds__(256) void agg_split_kernel(
        const float* __restrict__ h,
        const unsigned short* __restrict__ hb,
        const int* __restrict__ indptr, const int* __restrict__ esrc,
        const float* __restrict__ eps_p, int eps_idx,
        unsigned short* __restrict__ xout) {
    int node = blockIdx.x * 8 + (threadIdx.x >> 5);
    int lane = threadIdx.x & 31;
    if (node >= NT) return;
    float e1 = 1.0f + eps_p[eps_idx];
    float4 a = ((const float4*)h)[(size_t)node * 32 + lane];
    float s0 = e1 * a.x, s1 = e1 * a.y, s2 = e1 * a.z, s3 = e1 * a.w;
    int beg = indptr[node], end = indptr[node + 1];
    int j = beg;
    for (; j + 8 <= end; j += 8) {
        ushort4 v0 = *(const ushort4*)(hb + (size_t)esrc[j + 0] * 128 + lane * 4);
        ushort4 v1 = *(const ushort4*)(hb + (size_t)esrc[j + 1] * 128 + lane * 4);
        ushort4 v2 = *(const ushort4*)(hb + (size_t)esrc[j + 2] * 128 + lane * 4);
        ushort4 v3 = *(const ushort4*)(hb + (size_t)esrc[j + 3] * 128 + lane * 4);
        ushort4 v4 = *(const ushort4*)(hb + (size_t)esrc[j + 4] * 128 + lane * 4);
        ushort4 v5 = *(const ushort4*)(hb + (size_t)esrc[j + 5] * 128 + lane * 4);
        ushort4 v6 = *(const ushort4*)(hb + (size_t)esrc[j + 6] * 128 + lane * 4);
        ushort4 v7 = *(const ushort4*)(hb + (size_t)esrc[j + 7] * 128 + lane * 4);
        s0 += ((bf16_to_f32(v0.x) + bf16_to_f32(v1.x)) + (bf16_to_f32(v2.x) + bf16_to_f32(v3.x)))
            + ((bf16_to_f32(v4.x) + bf16_to_f32(v5.x)) + (bf16_to_f32(v6.x) + bf16_to_f32(v7.x)));
        s1 += ((bf16_to_f32(v0.y) + bf16_to_f32(v1.y)) + (bf16_to_f32(v2.y) + bf16_to_f32(v3.y)))
            + ((bf16_to_f32(v4.y) + bf16_to_f32(v5.y)) + (bf16_to_f32(v6.y) + bf16_to_f32(v7.y)));
        s2 += ((bf16_to_f32(v0.z) + bf16_to_f32(v1.z)) + (bf16_to_f32(v2.z) + bf16_to_f32(v3.z)))
            + ((bf16_to_f32(v4.z) + bf16_to_f32(v5.z)) + (bf16_to_f32(v6.z) + bf16_to_f32(v7.z)));
        s3 += ((bf16_to_f32(v0.w) + bf16_to_f32(v1.w)) + (bf16_to_f32(v2.w) + bf16_to_f32(v3.w)))
            + ((bf16_to_f32(v4.w) + bf16_to_f32(v5.w)) + (bf16_to_f32(v6.w) + bf16_to_f32(v7.w)));
    }
    for (; j + 2 <= end; j += 2) {
        ushort4 v0 = *(const ushort4*)(hb + (size_t)esrc[j + 0] * 128 + lane * 4);
        ushort4 v1 = *(const ushort4*)(hb + (size_t)esrc[j + 1] * 128 + lane * 4);
        s0 += bf16_to_f32(v0.x) + bf16_to_f32(v1.x);
        s1 += bf16_to_f32(v0.y) + bf16_to_f32(v1.y);
        s2 += bf16_to_f32(v0.z) + bf16_to_f32(v1.z);
        s3 += bf16_to_f32(v0.w) + bf16_to_f32(v1.w);
    }
    if (j < end) {
        ushort4 v0 = *(const ushort4*)(hb + (size_t)esrc[j] * 128 + lane * 4);
        s0 += bf16_to_f32(v0.x); s1 += bf16_to_f32(v0.y);
        s2 += bf16_to_f32(v0.z); s3 += bf16_to_f32(v0.w);
    }
    ushort4 hv, lv;
    hv.x = f32_to_bf16(s0); lv.x = f32_to_bf16(s0 - bf16_to_f32(hv.x));
    hv.y = f32_to_bf16(s1); lv.y = f32_to_bf16(s1 - bf16_to_f32(hv.y));
    hv.z = f32_to_bf16(s2); lv.z = f32_to_bf16(s2 - bf16_to_f32(hv.z));
    hv.w = f32_to_bf16(s3); lv.w = f32_to_bf16(s3 - bf16_to_f32(hv.w));
    *(ushort4*)(xout + (size_t)node * 256 + lane * 4) = hv;
    *(ushort4*)(xout + (size_t)node * 256 + 128 + lane * 4) = lv;
}

// ---------------------------------------------------------------------------
// Weight split + frag-major repack (see R4 comment).
// ---------------------------------------------------------------------------
__global__ __launch_bounds__(256) void bsplit_kernel(const float* __restrict__ Wa,
                                                     const float* __restrict__ Wb,
                                                     unsigned short* __restrict__ Bfrag) {
    int slot = blockIdx.x >> 3;
    int sub = blockIdx.x & 7;
    const float* W = (slot < 4) ? (Wa + (size_t)slot * DIM * DIM)
                                : (Wb + (size_t)(slot - 4) * DIM * DIM);
    unsigned short* out = Bfrag + (size_t)slot * 32768;
    for (int i = 0; i < 16; ++i) {
        int e = sub * 4096 + i * 256 + threadIdx.x;
        int kphys = e >> 7, n = e & 127;
        int k = kphys & 127;
        float wv = W[k * 128 + n];
        unsigned short hi = f32_to_bf16(wv);
        unsigned short val = (kphys < 128) ? hi : f32_to_bf16(wv - bf16_to_f32(hi));
        int nt = n >> 5, nin = n & 31;
        int kcp = kphys >> 4, kgp = (kphys >> 3) & 1, jj = kphys & 7;
        out[(size_t)(((nt * 16 + kcp) * 64) + kgp * 32 + nin) * 8 + jj] = val;
    }
}

// ---------------------------------------------------------------------------
// MFMA GEMM. ASPLIT: A from precomputed bf16 hi/lo rows. !ASPLIT: A from fp32
// + BN params computed per-block from gsumIn (fused bnparam). STATS: column
// sum/sumsq of output. EMITB: also write bf16 mirror of C.
// ---------------------------------------------------------------------------
template <int ASPLIT, int STATS, int RELU, int EMITB>
__global__ __launch_bounds__(256) void fused_gemm_kernel(
        const void* __restrict__ Asrc,
        const unsigned short* __restrict__ Bfrag,
        const float* __restrict__ bias,
        const float* __restrict__ gsumIn, const float* __restrict__ gamma,
        const float* __restrict__ beta,
        float* __restrict__ C, unsigned short* __restrict__ CBout,
        float* __restrict__ gsum, float* __restrict__ gsumsq) {
    __shared__ char smem[65536 + 1024];
    unsigned short* sB = (unsigned short*)smem;
    float* sBNa = (float*)(smem + 65536);
    float* sBNb = sBNa + 128;
    const int tid = threadIdx.x;
    const int w = tid >> 6, lane = tid & 63;
    const int nin = lane & 31, kg = lane >> 5;
    const int row0 = blockIdx.x * 128;
    const int myrow = row0 + w * 32 + nin;
    const int rowc = myrow < NT ? myrow : NT - 1;

    // stage whole B' into LDS
    {
        const uint4* Bg = (const uint4*)Bfrag;
        uint4* sB4 = (uint4*)smem;
#pragma unroll
        for (int i = 0; i < 16; ++i) sB4[tid + 256 * i] = Bg[tid + 256 * i];
    }

    s16x8 ahi[8], alo[8];
    if (ASPLIT) {
        const unsigned short* ar = (const unsigned short*)Asrc + (size_t)rowc * 256 + kg * 8;
#pragma unroll
        for (int kc = 0; kc < 8; ++kc) {
            ahi[kc] = *(const s16x8*)(ar + kc * 16);
            alo[kc] = *(const s16x8*)(ar + 128 + kc * 16);
        }
        __syncthreads();
    } else {
        if (tid < 128) {
            float mu = gsumIn[tid] * (1.0f / NT);
            float var = gsumIn[128 + tid] * (1.0f / NT) - mu * mu;
            float inv = rsqrtf(var + 1e-5f);
            float a = gamma[tid] * inv;
            sBNa[tid] = a;
            sBNb[tid] = beta[tid] - mu * a;
        }
        __syncthreads();   // sBN + B ready
        const float* yr = (const float*)Asrc + (size_t)rowc * 128 + kg * 8;
#pragma unroll
        for (int kc = 0; kc < 8; ++kc) {
            int c0 = kc * 16 + kg * 8;
            float4 y0 = *(const float4*)(yr + kc * 16);
            float4 y1 = *(const float4*)(yr + kc * 16 + 4);
            float4 a0 = *(const float4*)(sBNa + c0);
            float4 a1 = *(const float4*)(sBNa + c0 + 4);
            float4 b0 = *(const float4*)(sBNb + c0);
            float4 b1 = *(const float4*)(sBNb + c0 + 4);
            float t[8];
            t[0] = fmaxf(0.f, fmaf(y0.x, a0.x, b0.x));
            t[1] = fmaxf(0.f, fmaf(y0.y, a0.y, b0.y));
            t[2] = fmaxf(0.f, fmaf(y0.z, a0.z, b0.z));
            t[3] = fmaxf(0.f, fmaf(y0.w, a0.w, b0.w));
            t[4] = fmaxf(0.f, fmaf(y1.x, a1.x, b1.x));
            t[5] = fmaxf(0.f, fmaf(y1.y, a1.y, b1.y));
            t[6] = fmaxf(0.f, fmaf(y1.z, a1.z, b1.z));
            t[7] = fmaxf(0.f, fmaf(y1.w, a1.w, b1.w));
            union { s16x8 v; unsigned short u[8]; } H, L;
#pragma unroll
            for (int q = 0; q < 8; ++q) {
                H.u[q] = f32_to_bf16(t[q]);
                L.u[q] = f32_to_bf16(t[q] - bf16_to_f32(H.u[q]));
            }
            ahi[kc] = H.v; alo[kc] = L.v;
        }
    }

    f32x16 acc[4];
#pragma unroll
    for (int nt = 0; nt < 4; ++nt)
#pragma unroll
        for (int r = 0; r < 16; ++r) acc[nt][r] = 0.f;

#pragma unroll
    for (int nt = 0; nt < 4; ++nt) {
        const unsigned short* bp = sB + (size_t)(nt * 16) * 512 + lane * 8;
#pragma unroll
        for (int kc = 0; kc < 8; ++kc) {
            s16x8 b = *(const s16x8*)(bp + kc * 512);
            acc[nt] = __builtin_amdgcn_mfma_f32_32x32x16_bf16(ahi[kc], b, acc[nt], 0, 0, 0);
            acc[nt] = __builtin_amdgcn_mfma_f32_32x32x16_bf16(alo[kc], b, acc[nt], 0, 0, 0);
        }
#pragma unroll
        for (int kc = 0; kc < 8; ++kc) {
            s16x8 b = *(const s16x8*)(bp + (8 + kc) * 512);
            acc[nt] = __builtin_amdgcn_mfma_f32_32x32x16_bf16(ahi[kc], b, acc[nt], 0, 0, 0);
        }
    }

    const int rbase = row0 + w * 32 + 4 * kg;
#pragma unroll
    for (int nt = 0; nt < 4; ++nt) {
        int col = nt * 32 + nin;
        float bv = bias[col];
#pragma unroll
        for (int reg = 0; reg < 16; ++reg) {
            int gr = rbase + (reg & 3) + 8 * (reg >> 2);
            float v = acc[nt][reg] + bv;
            if (RELU) v = fmaxf(v, 0.f);
            if (gr < NT) {
                C[(size_t)gr * 128 + col] = v;
                if (EMITB) CBout[(size_t)gr * 128 + col] = f32_to_bf16(v);
            }
            acc[nt][reg] = (gr < NT) ? v : 0.f;
        }
    }

    if (STATS) {
        __syncthreads();
        float* ls = (float*)smem;
        ls[tid] = 0.f;
        __syncthreads();
#pragma unroll
        for (int nt = 0; nt < 4; ++nt) {
            int col = nt * 32 + nin;
            float s = 0.f, q = 0.f;
#pragma unroll
            for (int reg = 0; reg < 16; ++reg) { float v = acc[nt][reg]; s += v; q += v * v; }
            atomicAdd(&ls[col], s);
            atomicAdd(&ls[128 + col], q);
        }
        __syncthreads();
        if (tid < 128) {
            atomicAdd(&gsum[tid], ls[tid]);
            atomicAdd(&gsumsq[tid], ls[128 + tid]);
        }
    }
}

// ---------------------------------------------------------------------------
// Readout: 2 blocks per graph, 4-deep unrolled row accumulation, partials.
// ---------------------------------------------------------------------------
__global__ __launch_bounds__(256) void readout_kernel(const float* __restrict__ h,
                                                      const int* __restrict__ goff,
                                                      float* __restrict__ hgp,
                                                      int colOff) {
    int g = blockIdx.x >> 1, h2 = blockIdx.x & 1;
    int c = threadIdx.x & 127, rr = threadIdx.x >> 7;
    int beg = goff[g], end = goff[g + 1];
    int n = beg + h2 * 2 + rr;   // stride 4 across the block pair
    float a0 = 0.f, a1 = 0.f, a2 = 0.f, a3 = 0.f;
    for (; n + 12 < end; n += 16) {
        a0 += h[(size_t)n * 128 + c];
        a1 += h[(size_t)(n + 4) * 128 + c];
        a2 += h[(size_t)(n + 8) * 128 + c];
        a3 += h[(size_t)(n + 12) * 128 + c];
    }
    for (; n < end; n += 4) a0 += h[(size_t)n * 128 + c];
    float acc = (a0 + a1) + (a2 + a3);
    __shared__ float ls[256];
    ls[threadIdx.x] = acc;
    __syncthreads();
    if (threadIdx.x < 128)
        hgp[(size_t)h2 * NG * 256 + g * 256 + colOff + c] = ls[c] + ls[128 + c];
}

// ---------------------------------------------------------------------------
__global__ __launch_bounds__(128) void mlp_kernel(const float* __restrict__ hgp,
                                                  const float* __restrict__ oW1,
                                                  const float* __restrict__ ob1,
                                                  const float* __restrict__ oW2,
                                                  const float* __restrict__ ob2,
                                                  const float* __restrict__ oW3,
                                                  const float* __restrict__ ob3,
                                                  float* __restrict__ out) {
    int g = blockIdx.x, t = threadIdx.x;
    __shared__ float sh[256];
    __shared__ float z[128];
    sh[t] = hgp[g * 256 + t] + hgp[(size_t)NG * 256 + g * 256 + t];
    sh[t + 128] = hgp[g * 256 + 128 + t] + hgp[(size_t)NG * 256 + g * 256 + 128 + t];
    __syncthreads();
    float acc = ob1[t];
    for (int k = 0; k < 256; ++k) acc = fmaf(sh[k], oW1[k * 128 + t], acc);
    float z1 = fmaxf(acc, 0.f);
    z[t] = z1;
    __syncthreads();
    acc = ob2[t];
    for (int k = 0; k < 128; ++k) acc = fmaf(z[k], oW2[k * 128 + t], acc);
    float z2 = fmaxf(acc, 0.f);
    float p = z2 * oW3[t];
    for (int off = 32; off > 0; off >>= 1) p += __shfl_down(p, off, 64);
    __shared__ float wsum[2];
    if ((t & 63) == 0) wsum[t >> 6] = p;
    __syncthreads();
    if (t == 0) out[g] = wsum[0] + wsum[1] + ob3[0];
}

// ---------------------------------------------------------------------------
extern "C" void kernel_launch(void* const* d_in, const int* in_sizes, int n_in,
                              void* d_out, int out_size, void* d_ws, size_t ws_size,
                              hipStream_t stream) {
    (void)in_sizes; (void)n_in; (void)out_size; (void)ws_size;
    const float* feats = (const float*)d_in[0];
    const int*   src   = (const int*)d_in[1];
    const int*   dst   = (const int*)d_in[2];
    const int*   gid   = (const int*)d_in[3];
    const float* epsp  = (const float*)d_in[5];
    const float* Wa    = (const float*)d_in[6];
    const float* ba    = (const float*)d_in[7];
    const float* bng   = (const float*)d_in[8];
    const float* bnb   = (const float*)d_in[9];
    const float* Wb    = (const float*)d_in[10];
    const float* bb    = (const float*)d_in[11];
    const float* oW1   = (const float*)d_in[12];
    const float* ob1   = (const float*)d_in[13];
    const float* oW2   = (const float*)d_in[14];
    const float* ob2   = (const float*)d_in[15];
    const float* oW3   = (const float*)d_in[16];
    const float* ob3   = (const float*)d_in[17];
    float* out = (float*)d_out;

    char* p = (char*)d_ws;
    auto carve = [&](size_t bytes) -> void* {
        void* r = (void*)p;
        p += (bytes + 255) & ~(size_t)255;
        return r;
    };
    unsigned short* Asplit = (unsigned short*)carve((size_t)NT * 256 * 2);
    float* bufY    = (float*)carve((size_t)NT * DIM * 4);
    float* bufH    = (float*)carve((size_t)NT * DIM * 4);
    unsigned short* featsB = (unsigned short*)carve((size_t)NT * DIM * 2);
    unsigned short* hB     = (unsigned short*)carve((size_t)NT * DIM * 2);
    unsigned short* Bfrag  = (unsigned short*)carve((size_t)8 * 32768 * 2);
    int*   esrc2    = (int*)carve((size_t)2 * NE * 4);
    unsigned int* part2 = (unsigned int*)carve((size_t)2 * NE * 4);
    int*   hcoarse2 = (int*)carve((size_t)2 * HCN * 4);
    int*   offbuf2  = (int*)carve((size_t)2 * HCN * 4);
    int*   bb2      = (int*)carve((size_t)2 * (NB + 1) * 4);
    int*   indptr2  = (int*)carve((size_t)2 * (NT + 1) * 4);
    int*   goff     = (int*)carve((size_t)(NG + 1) * 4);
    float* gsumAll  = (float*)carve((size_t)4 * 256 * 4);  // 4 layers x (sum|sumsq)
    float* hgp      = (float*)carve((size_t)2 * NG * 256 * 4);

    const int CB = (NT * 32 + 255) / 256;

    ranges_kernel<<<1, 256, 0, stream>>>(gid, goff);
    bsplit_kernel<<<64, 256, 0, stream>>>(Wa, Wb, Bfrag);
    tobf16_kernel<<<CB, 256, 0, stream>>>(feats, featsB);
    hipMemsetAsync(gsumAll, 0, (size_t)4 * 256 * 4, stream);

    // CSR for both edge types, up front
    csr_part_hist_kernel<<<dim3(PB, 2), 256, 0, stream>>>(dst, hcoarse2);
    csr_scan_kernel<<<2, 1024, 0, stream>>>(hcoarse2, offbuf2, bb2, indptr2);
    csr_scatter_kernel<<<dim3(PB, 2), 256, 0, stream>>>(src, dst, offbuf2, part2);
    csr_finalize_kernel<<<dim3(NB, 2), 256, 0, stream>>>(part2, bb2, indptr2, esrc2);

    for (int e = 0; e < 2; ++e) {
        const int* indptr = indptr2 + (size_t)e * (NT + 1);
        const int* esrc   = esrc2 + (size_t)e * NE;
        for (int l = 0; l < 2; ++l) {
            int wi = e * 2 + l;
            float* gsum = gsumAll + wi * 256;
            float* gsumsq = gsum + 128;
            const float* hSrc = (l == 0) ? feats : bufH;
            const unsigned short* hbSrc = (l == 0) ? featsB : hB;
            // standalone edge-parallel aggregation (R7 post-mortem: in-GEMM
            // gather loses 16x parallel width and regresses 58->90 us)
            agg_split_kernel<<<(NT + 7) / 8, 256, 0, stream>>>(
                hSrc, hbSrc, indptr, esrc, epsp, wi, Asplit);
            // GEMM1: A from Asplit, stats for BN
            fused_gemm_kernel<1, 1, 0, 0><<<GEMM_B, 256, 0, stream>>>(
                Asplit, Bfrag + (size_t)wi * 32768, ba + (size_t)wi * DIM,
                nullptr, nullptr, nullptr, bufY, nullptr, gsum, gsumsq);
            // GEMM2: fused BN-param calc + BN+ReLU on A (+bf16 mirror on l==0)
            if (l == 0)
                fused_gemm_kernel<0, 0, 1, 1><<<GEMM_B, 256, 0, stream>>>(
                    bufY, Bfrag + (size_t)(4 + wi) * 32768, bb + (size_t)wi * DIM,
                    gsum, bng + (size_t)wi * DIM, bnb + (size_t)wi * DIM,
                    bufH, hB, nullptr, nullptr);
            else
                fused_gemm_kernel<0, 0, 0, 0><<<GEMM_B, 256, 0, stream>>>(
                    bufY, Bfrag + (size_t)(4 + wi) * 32768, bb + (size_t)wi * DIM,
                    gsum, bng + (size_t)wi * DIM, bnb + (size_t)wi * DIM,
                    bufH, nullptr, nullptr, nullptr);
        }
        readout_kernel<<<NG * 2, 256, 0, stream>>>(bufH, goff, hgp, e * 128);
    }
    mlp_kernel<<<NG, 128, 0, stream>>>(hgp, oW1, ob1, oW2, ob2, oW3, ob3, out);
}